// Round 17
// baseline (128.263 us; speedup 1.0000x reference)
//
#include <hip/hip_runtime.h>
#include <hip/hip_bf16.h>

// Sizes
#define NB 256
#define NS 30
#define NW 10
#define SYM 128
#define HID 512
#define ENT 64
#define ROLE 32

typedef unsigned short ushortT;
typedef __attribute__((ext_vector_type(8))) short short8v;   // 8 bf16
typedef __attribute__((ext_vector_type(4))) float f32x4;

// Workspace offsets (floats; bf16 arrays use 2 elems per float slot)
static const size_t OF_SENTB = 0;         // 7680*128 bf16 -> 491520 fl
static const size_t OF_QEMBB = 491520;    // 256*128 bf16 -> 16384 fl
static const size_t OF_W1A   = 507904;    // 9*512*128 bf16 -> 294912 fl
static const size_t OF_W2TE  = 802816;    // 3*64*512 bf16 -> 49152 fl
static const size_t OF_W2TR  = 851968;    // 6*32*512 bf16 -> 49152 fl
static const size_t OF_FWMB  = 901120;    // 64*2048 bf16 -> 65536 fl  (fwm^T [f][e*32+r])
static const size_t OF_E1    = 966656;    // 7680*64 x2 (stride 491520)
static const size_t OF_R1    = 1949696;   // 7680*32 x3 (stride 245760)
static const size_t OF_QE1   = 2686976;   // 256*64
static const size_t OF_QR1   = 2703360;   // 256*32 x3 (stride 8192)
static const size_t OF_PP    = 2727936;   // 3 * 7680*64 = 1,474,560
static const size_t OF_FN2   = 4202496;   // 8 partials
static const size_t OF_G     = 4202624;   // 3*256*64*64 = 3,145,728

__device__ __forceinline__ ushortT f2bf(float x) {
  unsigned u = __float_as_uint(x);
  unsigned r = (u + 0x7fffu + ((u >> 16) & 1u)) >> 16;
  return (ushortT)r;
}
__device__ __forceinline__ float bf2f(ushortT h) {
  return __uint_as_float((unsigned)h << 16);
}
__device__ __forceinline__ float ftanh(float x) {
  float t = __expf(2.f * x);
  return 1.f - 2.f * __builtin_amdgcn_rcpf(t + 1.f);
}
__device__ __forceinline__ float dot4(const float4& a, const float4& b) {
  return a.x * b.x + a.y * b.y + a.z * b.z + a.w * b.w;
}
__device__ __forceinline__ float wreduce64(float v) {
  #pragma unroll
  for (int o = 32; o > 0; o >>= 1) v += __shfl_xor(v, o);
  return v;
}

// ---------------- unified prep: embed + all transposes/converts + fnorm partials ----------------
__global__ __launch_bounds__(256) void prep_k(
    const int* __restrict__ story, const int* __restrict__ query,
    const float* __restrict__ WE, const float* __restrict__ PE,
    const float* __restrict__ ueW1, const float* __restrict__ urW1,
    const float* __restrict__ ieW1, const float* __restrict__ irW1,
    const float* __restrict__ ueW2, const float* __restrict__ urW2,
    const float* __restrict__ ieW2, const float* __restrict__ irW2,
    const float* __restrict__ fwm,
    ushortT* __restrict__ sentb, ushortT* __restrict__ qembb,
    ushortT* __restrict__ W1A, ushortT* __restrict__ W2TE,
    ushortT* __restrict__ W2TR, ushortT* __restrict__ fwmBT,
    float* __restrict__ fn2) {
  __shared__ float tl[64 * 65];
  __shared__ float red[4];
  int bx = blockIdx.x, tid = threadIdx.x;
  if (bx < 3968) {
    int row = bx * 2 + (tid >> 7);
    int e = tid & 127;
    const int* idx; ushortT* dst;
    if (row < 7680) { idx = story + (size_t)row * NW; dst = sentb + (size_t)row * SYM; }
    else            { idx = query + (size_t)(row - 7680) * NW; dst = qembb + (size_t)(row - 7680) * SYM; }
    float acc = 0.f;
    #pragma unroll
    for (int w = 0; w < NW; ++w) acc += WE[idx[w] * SYM + e] * PE[w * SYM + e];
    dst[e] = f2bf(acc);
    return;
  }
  bx -= 3968;
  const float* src; ushortT* dst; int R, C, tr0, tc0;
  if (bx < 144) {
    int h = bx >> 4, t = bx & 15;
    src = (h < 2) ? ueW1 + (size_t)h * 65536 : (h < 5) ? urW1 + (size_t)(h - 2) * 65536
        : (h == 5) ? ieW1 : irW1 + (size_t)(h - 6) * 65536;
    dst = W1A + (size_t)h * 65536;
    R = 128; C = 512; tr0 = (t >> 3) * 64; tc0 = (t & 7) * 64;
  } else if (bx < 168) {
    int h = (bx - 144) >> 3, t = (bx - 144) & 7;
    src = (h < 2) ? ueW2 + (size_t)h * 32768 : ieW2;
    dst = W2TE + (size_t)h * 32768;
    R = 512; C = 64; tr0 = t * 64; tc0 = 0;
  } else if (bx < 216) {
    int h = (bx - 168) >> 3, t = (bx - 168) & 7;
    src = (h < 3) ? urW2 + (size_t)h * 16384 : irW2 + (size_t)(h - 3) * 16384;
    dst = W2TR + (size_t)h * 16384;
    R = 512; C = 32; tr0 = t * 64; tc0 = 0;
  } else if (bx < 248) {
    int t = bx - 216;
    src = fwm; dst = fwmBT; R = 2048; C = 64; tr0 = t * 64; tc0 = 0;
  } else {
    int blk = bx - 248;
    const float4* f4 = reinterpret_cast<const float4*>(fwm) + blk * 4096;
    float a = 0.f;
    for (int i = tid; i < 4096; i += 256) {
      float4 v = f4[i];
      a += v.x*v.x + v.y*v.y + v.z*v.z + v.w*v.w;
    }
    a = wreduce64(a);
    if ((tid & 63) == 0) red[tid >> 6] = a;
    __syncthreads();
    if (tid == 0) fn2[blk] = red[0] + red[1] + red[2] + red[3];
    return;
  }
  int TC = (C < 64) ? C : 64;
  int n = 64 * TC;
  for (int i = tid; i < n; i += 256) {
    int r = i / TC, c = i % TC;
    tl[r * 65 + c] = src[(size_t)(tr0 + r) * C + tc0 + c];
  }
  __syncthreads();
  for (int i = tid; i < n; i += 256) {
    int c = i >> 6, r = i & 63;
    dst[(size_t)(tc0 + c) * R + tr0 + r] = f2bf(tl[r * 65 + c]);
  }
}

// ---------------- MFMA fused 2-layer MLP (512 threads / 8 waves for TLP) ----------------
__global__ __launch_bounds__(512, 8) void mlpm_k(
    const ushortT* __restrict__ sentB, const ushortT* __restrict__ qembB,
    const ushortT* __restrict__ W1A,
    const float* __restrict__ ueb1, const float* __restrict__ urb1,
    const float* __restrict__ ieb1, const float* __restrict__ irb1,
    const ushortT* __restrict__ W2TE, const ushortT* __restrict__ W2TR,
    const float* __restrict__ ueb2, const float* __restrict__ urb2,
    const float* __restrict__ ieb2, const float* __restrict__ irb2,
    float* __restrict__ E1, float* __restrict__ R1,
    float* __restrict__ QE1, float* __restrict__ QR1) {
  __shared__ __align__(16) ushortT Hl[32 * 520];
  int y = blockIdx.y;
  bool isQ = y >= 5;
  if (isQ && blockIdx.x >= 8) return;
  int r0 = blockIdx.x * 32, tid = threadIdx.x;
  int wave = tid >> 6, lane = tid & 63;
  int lrow = lane & 15;
  int kgrp = lane >> 4;
  const ushortT* Xb = isQ ? qembB : sentB;
  const ushortT* W1h = W1A + (size_t)y * 65536;
  const float* b1 = (y < 2) ? ueb1 + y * 512 : (y < 5) ? urb1 + (y - 2) * 512
                  : (y == 5) ? ieb1 : irb1 + (y - 6) * 512;
  bool isE = (y < 2) || (y == 5);

  int cw = wave * 64;                        // 8 waves x 64 GEMM1 cols

  short8v afr[2][4];
  #pragma unroll
  for (int rt = 0; rt < 2; ++rt) {
    const ushortT* arow = Xb + (size_t)(r0 + rt * 16 + lrow) * 128 + kgrp * 8;
    #pragma unroll
    for (int kt = 0; kt < 4; ++kt)
      afr[rt][kt] = *reinterpret_cast<const short8v*>(arow + kt * 32);
  }

  float bb4[4];
  #pragma unroll
  for (int ct = 0; ct < 4; ++ct) bb4[ct] = b1[cw + ct * 16 + lrow];

  // GEMM1: 4 col-tiles; each B-frag feeds 2 MFMAs (row-tiles)
  #pragma unroll
  for (int ct = 0; ct < 4; ++ct) {
    int c0 = cw + ct * 16;
    const ushortT* bcol = W1h + (size_t)(c0 + lrow) * 128 + kgrp * 8;
    short8v bf0 = *reinterpret_cast<const short8v*>(bcol);
    short8v bf1 = *reinterpret_cast<const short8v*>(bcol + 32);
    short8v bf2 = *reinterpret_cast<const short8v*>(bcol + 64);
    short8v bf3 = *reinterpret_cast<const short8v*>(bcol + 96);
    f32x4 aA[2] = {{0.f,0.f,0.f,0.f},{0.f,0.f,0.f,0.f}};
    f32x4 aB[2] = {{0.f,0.f,0.f,0.f},{0.f,0.f,0.f,0.f}};
    #pragma unroll
    for (int rt = 0; rt < 2; ++rt) {
      aA[rt] = __builtin_amdgcn_mfma_f32_16x16x32_bf16(afr[rt][0], bf0, aA[rt], 0, 0, 0);
      aB[rt] = __builtin_amdgcn_mfma_f32_16x16x32_bf16(afr[rt][1], bf1, aB[rt], 0, 0, 0);
      aA[rt] = __builtin_amdgcn_mfma_f32_16x16x32_bf16(afr[rt][2], bf2, aA[rt], 0, 0, 0);
      aB[rt] = __builtin_amdgcn_mfma_f32_16x16x32_bf16(afr[rt][3], bf3, aB[rt], 0, 0, 0);
    }
    int lcol = c0 + lrow;
    float bb = bb4[ct];
    #pragma unroll
    for (int rt = 0; rt < 2; ++rt)
      #pragma unroll
      for (int i = 0; i < 4; ++i) {
        float hv = ftanh(aA[rt][i] + aB[rt][i] + bb);
        Hl[(rt * 16 + kgrp * 4 + i) * 520 + lcol] = f2bf(hv);
      }
  }
  __syncthreads();

  if (isE) {   // O=64: wave = (row-tile rt, col-quarter cq)
    int slot = (y == 5) ? 2 : y;
    const ushortT* W2h = W2TE + (size_t)slot * 32768;
    const float* b2 = (y == 5) ? ieb2 : ueb2 + y * 64;
    float* Out = (y == 5) ? QE1 : E1 + (size_t)y * 491520;
    int rt = wave >> 2, cq = wave & 3;
    int col = cq * 16 + lrow;
    f32x4 accA = {0.f,0.f,0.f,0.f}, accB = {0.f,0.f,0.f,0.f};
    const ushortT* wc = W2h + (size_t)col * 512;
    #pragma unroll
    for (int kt = 0; kt < 16; kt += 2) {
      int kb0 = kt * 32 + kgrp * 8;
      int kb1 = kb0 + 32;
      short8v a0 = *reinterpret_cast<const short8v*>(&Hl[(rt * 16 + lrow) * 520 + kb0]);
      short8v a1 = *reinterpret_cast<const short8v*>(&Hl[(rt * 16 + lrow) * 520 + kb1]);
      short8v b0 = *reinterpret_cast<const short8v*>(wc + kb0);
      short8v b1v = *reinterpret_cast<const short8v*>(wc + kb1);
      accA = __builtin_amdgcn_mfma_f32_16x16x32_bf16(a0, b0, accA, 0, 0, 0);
      accB = __builtin_amdgcn_mfma_f32_16x16x32_bf16(a1, b1v, accB, 0, 0, 0);
    }
    float bb = b2[col];
    #pragma unroll
    for (int i = 0; i < 4; ++i) {
      int grow = r0 + rt * 16 + kgrp * 4 + i;
      Out[(size_t)grow * 64 + col] = ftanh(accA[i] + accB[i] + bb);
    }
  } else {     // O=32: waves with cq<2 active
    int slot = (y < 5) ? (y - 2) : (3 + y - 6);
    const ushortT* W2h = W2TR + (size_t)slot * 16384;
    const float* b2 = (y < 5) ? urb2 + (y - 2) * 32 : irb2 + (y - 6) * 32;
    float* Out = (y < 5) ? R1 + (size_t)(y - 2) * 245760 : QR1 + (size_t)(y - 6) * 8192;
    int rt = wave >> 2, cq = wave & 3;
    if (cq < 2) {
      int col = cq * 16 + lrow;
      f32x4 accA = {0.f, 0.f, 0.f, 0.f}, accB = {0.f, 0.f, 0.f, 0.f};
      const ushortT* wc = W2h + (size_t)col * 512;
      #pragma unroll
      for (int kt = 0; kt < 16; kt += 2) {
        int kb0 = kt * 32 + kgrp * 8;
        int kb1 = kb0 + 32;
        short8v a0 = *reinterpret_cast<const short8v*>(&Hl[(rt * 16 + lrow) * 520 + kb0]);
        short8v a1 = *reinterpret_cast<const short8v*>(&Hl[(rt * 16 + lrow) * 520 + kb1]);
        short8v b0 = *reinterpret_cast<const short8v*>(wc + kb0);
        short8v b1v = *reinterpret_cast<const short8v*>(wc + kb1);
        accA = __builtin_amdgcn_mfma_f32_16x16x32_bf16(a0, b0, accA, 0, 0, 0);
        accB = __builtin_amdgcn_mfma_f32_16x16x32_bf16(a1, b1v, accB, 0, 0, 0);
      }
      float bb = b2[col];
      #pragma unroll
      for (int i = 0; i < 4; ++i) {
        int grow = r0 + rt * 16 + kgrp * 4 + i;
        Out[(size_t)grow * 32 + col] = ftanh(accA[i] + accB[i] + bb);
      }
    }
  }
}

// ---------------- MFMA P-stage (bx<480) + G-stage (bx>=480) ----------------
__global__ __launch_bounds__(256) void pstage_k(const ushortT* __restrict__ fwmBT,
    const float* __restrict__ e1g, const float* __restrict__ e2g,
    const float* __restrict__ r1g, const float* __restrict__ r2g, const float* __restrict__ r3g,
    const float* __restrict__ qr1g, const float* __restrict__ qr2g, const float* __restrict__ qr3g,
    float* __restrict__ Pp, float* __restrict__ Gg) {
  __shared__ __align__(16) float e1t[16 * 68], e2t[16 * 68];
  int bx = blockIdx.x, tid = threadIdx.x;
  int wave = tid >> 6, lane = tid & 63;
  int c = lane & 15, kg = lane >> 4;
  int f0 = wave * 16;
  const f32x4 zero = {0,0,0,0};

  if (bx >= 480) {
    int b = bx - 480;
    short8v qa = {0,0,0,0,0,0,0,0};
    if (c < 3) {
      const float* qr = ((c == 0) ? qr1g : (c == 1) ? qr2g : qr3g) + (size_t)b * 32 + kg * 8;
      ushortT* p = (ushortT*)&qa;
      #pragma unroll
      for (int j = 0; j < 8; ++j) p[j] = f2bf(qr[j]);
    }
    const ushortT* bbase = fwmBT + (size_t)(f0 + c) * 2048 + kg * 8;
    float* g0 = Gg + (size_t)b * 4096 + f0 + c;
    for (int e = 0; e < 64; ++e) {
      short8v B = *reinterpret_cast<const short8v*>(bbase + (size_t)e * 32);
      f32x4 T = __builtin_amdgcn_mfma_f32_16x16x32_bf16(qa, B, zero, 0, 0, 0);
      if (kg == 0) {
        g0[e * 64]           = T[0];
        g0[1048576 + e * 64] = T[1];
        g0[2097152 + e * 64] = T[2];
      }
    }
    return;
  }

  int rb = bx;
  {
    int row = tid >> 4, c4 = tid & 15;
    float4 v1 = *reinterpret_cast<const float4*>(e1g + ((size_t)rb * 16 + row) * 64 + c4 * 4);
    float4 v2 = *reinterpret_cast<const float4*>(e2g + ((size_t)rb * 16 + row) * 64 + c4 * 4);
    *reinterpret_cast<float4*>(&e1t[row * 68 + c4 * 4]) = v1;
    *reinterpret_cast<float4*>(&e2t[row * 68 + c4 * 4]) = v2;
  }
  size_t rbase = ((size_t)rb * 16 + c) * 32 + kg * 8;
  short8v rA, rB, rC;
  {
    float4 x0 = *reinterpret_cast<const float4*>(r1g + rbase);
    float4 x1 = *reinterpret_cast<const float4*>(r1g + rbase + 4);
    ushortT* p = (ushortT*)&rA;
    p[0]=f2bf(x0.x); p[1]=f2bf(x0.y); p[2]=f2bf(x0.z); p[3]=f2bf(x0.w);
    p[4]=f2bf(x1.x); p[5]=f2bf(x1.y); p[6]=f2bf(x1.z); p[7]=f2bf(x1.w);
    x0 = *reinterpret_cast<const float4*>(r2g + rbase);
    x1 = *reinterpret_cast<const float4*>(r2g + rbase + 4);
    p = (ushortT*)&rB;
    p[0]=f2bf(x0.x); p[1]=f2bf(x0.y); p[2]=f2bf(x0.z); p[3]=f2bf(x0.w);
    p[4]=f2bf(x1.x); p[5]=f2bf(x1.y); p[6]=f2bf(x1.z); p[7]=f2bf(x1.w);
    x0 = *reinterpret_cast<const float4*>(r3g + rbase);
    x1 = *reinterpret_cast<const float4*>(r3g + rbase + 4);
    p = (ushortT*)&rC;
    p[0]=f2bf(x0.x); p[1]=f2bf(x0.y); p[2]=f2bf(x0.z); p[3]=f2bf(x0.w);
    p[4]=f2bf(x1.x); p[5]=f2bf(x1.y); p[6]=f2bf(x1.z); p[7]=f2bf(x1.w);
  }
  __syncthreads();
  const ushortT* bbase = fwmBT + (size_t)(f0 + c) * 2048 + kg * 8;
  f32x4 P1 = {0,0,0,0}, P2 = {0,0,0,0}, P3 = {0,0,0,0};
  int r0 = kg * 4;
  for (int e4 = 0; e4 < 16; ++e4) {
    float4 ea[4], eb[4];
    #pragma unroll
    for (int i = 0; i < 4; ++i) {
      ea[i] = *reinterpret_cast<const float4*>(&e1t[(r0 + i) * 68 + e4 * 4]);
      eb[i] = *reinterpret_cast<const float4*>(&e2t[(r0 + i) * 68 + e4 * 4]);
    }
    #pragma unroll
    for (int sub = 0; sub < 4; ++sub) {
      int e = e4 * 4 + sub;
      short8v B = *reinterpret_cast<const short8v*>(bbase + (size_t)e * 32);
      f32x4 T1 = __builtin_amdgcn_mfma_f32_16x16x32_bf16(rA, B, zero, 0, 0, 0);
      f32x4 T2 = __builtin_amdgcn_mfma_f32_16x16x32_bf16(rB, B, zero, 0, 0, 0);
      f32x4 T3 = __builtin_amdgcn_mfma_f32_16x16x32_bf16(rC, B, zero, 0, 0, 0);
      #pragma unroll
      for (int i = 0; i < 4; ++i) {
        float e1v = reinterpret_cast<const float*>(&ea[i])[sub];
        float e2v = reinterpret_cast<const float*>(&eb[i])[sub];
        P1[i] += e1v * T1[i];
        P2[i] += e1v * T2[i];
        P3[i] += e2v * T3[i];
      }
    }
  }
  #pragma unroll
  for (int i = 0; i < 4; ++i) {
    size_t row = (size_t)rb * 16 + kg * 4 + i;
    Pp[row * 64 + f0 + c]               = P1[i];
    Pp[491520 + row * 64 + f0 + c]      = P2[i];
    Pp[2 * 491520 + row * 64 + f0 + c]  = P3[i];
  }
}

// ---------------- scan: gram(bf16 hi/lo M) + MFMA propagation + inference ----------------
__global__ __launch_bounds__(1024) void scan_k(
    const float* __restrict__ Pp, const float* __restrict__ Gg,
    const float* __restrict__ e1g, const float* __restrict__ e2g,
    const float* __restrict__ r1g, const float* __restrict__ r2g, const float* __restrict__ r3g,
    const float* __restrict__ qe1g, const float* __restrict__ qr1g, const float* __restrict__ qr2g,
    const float* __restrict__ qr3g, const float* __restrict__ fn2p,
    const float* __restrict__ lng, const float* __restrict__ lnb, const float* __restrict__ Zg,
    float* __restrict__ out) {
  __shared__ __align__(16) ushortT MBs[2][9][1280];     // [hi/lo][ph*3+kk][row*40+col] bf16 M
  __shared__ __align__(16) ushortT vTb[2][2][2560];     // [buf][hi/lo][f*40+sp]
  __shared__ float wLx[2048];                            // w relay
  __shared__ float partBuf[1024];
  __shared__ __align__(16) float e1L[2040], e2L[2040];  // [30][68]
  __shared__ __align__(16) float v1L[2040], v2L[2040], v3L[2040];
  __shared__ __align__(16) float r1L[1080], r2L[1080], r3L[1080];  // [30][36]
  __shared__ float uv[64], qv[96], alf[96], siL[64], rqL[272];
  __shared__ float redL[16];
  int b = blockIdx.x, tid = threadIdx.x;
  int wave = tid >> 6, lane = tid & 63;
  int col = lane & 15, kgrp = lane >> 4;
  bool wact = wave < 12;
  int kk = wave >> 2, idx = wave & 3, st = idx >> 1, fp = idx & 1;

  // ---- staging ----
  for (int i = tid; i < 1680; i += 1024) {
    if (i < 480) {
      int ss = i >> 4, c4 = i & 15;
      *reinterpret_cast<float4*>(&e1L[ss * 68 + c4 * 4]) =
          *reinterpret_cast<const float4*>(e1g + (size_t)b * 1920 + i * 4);
    } else if (i < 960) {
      int j = i - 480;
      int ss = j >> 4, c4 = j & 15;
      *reinterpret_cast<float4*>(&e2L[ss * 68 + c4 * 4]) =
          *reinterpret_cast<const float4*>(e2g + (size_t)b * 1920 + j * 4);
    } else {
      int j = i - 960;
      int which = j / 240, jj = j - which * 240;
      int ss = jj >> 3, c4 = jj & 7;
      float* dstL = (which == 0) ? r1L : (which == 1) ? r2L : r3L;
      const float* srcG = (which == 0) ? r1g : (which == 1) ? r2g : r3g;
      *reinterpret_cast<float4*>(&dstL[ss * 36 + c4 * 4]) =
          *reinterpret_cast<const float4*>(srcG + (size_t)b * 960 + jj * 4);
    }
  }
  if (tid >= 128 && tid < 224) {
    int t = tid - 128, sst = t >> 5, k = t & 31;
    const float* qrg = (sst == 0) ? qr1g : ((sst == 1) ? qr2g : qr3g);
    qv[t] = qrg[(size_t)b * 32 + k];
  }
  for (int i = tid; i < 7200; i += 1024) {
    int m = i / 400, rr = i - m * 400;
    int hl = m / 9, mat = m - hl * 9;
    int r, c;
    if (rr < 320) { r = rr / 10; c = 30 + rr % 10; }
    else { int q = rr - 320; r = 30 + q / 40; c = q % 40; }
    MBs[hl][mat][r * 40 + c] = 0;
  }
  f32x4 Ht[2] = {{0.f,0.f,0.f,0.f},{0.f,0.f,0.f,0.f}};
  float aT[2][4] = {{0,0,0,0},{0,0,0,0}};
  if (wact) {
    #pragma unroll
    for (int t = 0; t < 2; ++t)
      #pragma unroll
      for (int i = 0; i < 4; ++i) {
        int srow = st * 16 + kgrp * 4 + i;
        int f = (fp * 2 + t) * 16 + col;
        Ht[t][i] = (srow < 30) ? Pp[(size_t)kk * 491520 + (size_t)b * 1920 + srow * 64 + f] : 0.f;
      }
  }
  __syncthreads();

  // ---- gram -> bf16 hi/lo M ; rqL ----
  if (tid < 900) {
    int si = tid / 30, sj = tid - si * 30;
    float g11 = 0, g12 = 0, g21 = 0, g22 = 0;
    {
      const float4* A1 = reinterpret_cast<const float4*>(&e1L[si * 68]);
      const float4* A2 = reinterpret_cast<const float4*>(&e2L[si * 68]);
      const float4* C1 = reinterpret_cast<const float4*>(&e1L[sj * 68]);
      const float4* C2 = reinterpret_cast<const float4*>(&e2L[sj * 68]);
      #pragma unroll 4
      for (int i = 0; i < 16; ++i) {
        float4 a1v = A1[i], a2v = A2[i], c1v = C1[i], c2v = C2[i];
        g11 += dot4(a1v, c1v); g12 += dot4(a1v, c2v);
        g21 += dot4(a2v, c1v); g22 += dot4(a2v, c2v);
      }
    }
    float R11=0,R12=0,R13=0,R21=0,R22=0,R23=0,R31=0,R32=0,R33=0;
    {
      const float4* X1 = reinterpret_cast<const float4*>(&r1L[si * 36]);
      const float4* X2 = reinterpret_cast<const float4*>(&r2L[si * 36]);
      const float4* X3 = reinterpret_cast<const float4*>(&r3L[si * 36]);
      const float4* Y1 = reinterpret_cast<const float4*>(&r1L[sj * 36]);
      const float4* Y2 = reinterpret_cast<const float4*>(&r2L[sj * 36]);
      const float4* Y3 = reinterpret_cast<const float4*>(&r3L[sj * 36]);
      #pragma unroll 4
      for (int i = 0; i < 8; ++i) {
        float4 x1 = X1[i], x2 = X2[i], x3 = X3[i];
        float4 y1 = Y1[i], y2 = Y2[i], y3 = Y3[i];
        R11 += dot4(x1, y1); R12 += dot4(x1, y2); R13 += dot4(x1, y3);
        R21 += dot4(x2, y1); R22 += dot4(x2, y2); R23 += dot4(x2, y3);
        R31 += dot4(x3, y1); R32 += dot4(x3, y2); R33 += dot4(x3, y3);
      }
    }
    float vals[9];
    vals[0] = g11 * R11; vals[1] = g11 * R21; vals[2] = g21 * R31;
    vals[3] = g11 * R12; vals[4] = g11 * R22; vals[5] = g21 * R32;
    vals[6] = g12 * R13; vals[7] = g12 * R23; vals[8] = g22 * R33;
    int o = si * 40 + sj;
    #pragma unroll
    for (int m = 0; m < 9; ++m) {
      ushortT hi = f2bf(vals[m]);
      float res = vals[m] - bf2f(hi);
      MBs[0][m][o] = hi;
      MBs[1][m][o] = f2bf(res);
    }
  } else {
    #pragma unroll
    for (int ch = 0; ch < 3; ++ch) {
      int t = (tid - 900) + ch * 124;
      if (t < 270) {
        int sst = t / 90, rem = t - sst * 90;
        int k = rem / 30, s2 = rem - k * 30;
        const float* rL = (k == 0) ? r1L : (k == 1) ? r2L : r3L;
        const float* qp = qv + sst * 32;
        float a = 0.f;
        #pragma unroll 8
        for (int r = 0; r < 32; ++r) a += rL[s2 * 36 + r] * qp[r];
        rqL[sst * 90 + k * 30 + s2] = a;
      }
    }
  }
  float eP[2][4] = {{0,0,0,0},{0,0,0,0}};
  if (wact && kk != 1) {
    const float* eSrc = (kk == 0) ? e2L : e1L;
    #pragma unroll
    for (int t = 0; t < 2; ++t)
      #pragma unroll
      for (int i = 0; i < 4; ++i) {
        int srow = st * 16 + kgrp * 4 + i;
        if (srow < 30) eP[t][i] = eSrc[srow * 68 + (fp * 2 + t) * 16 + col];
      }
  }
  __syncthreads();

  short8v Ah0, Al0, Ah1, Al1, Ah2, Al2;
  if (wact) {
    int ao = (st * 16 + col) * 40 + kgrp * 8;
    Ah0 = *reinterpret_cast<const short8v*>(&MBs[0][kk][ao]);
    Al0 = *reinterpret_cast<const short8v*>(&MBs[1][kk][ao]);
    Ah1 = *reinterpret_cast<const short8v*>(&MBs[0][3 + kk][ao]);
    Al1 = *reinterpret_cast<const short8v*>(&MBs[1][3 + kk][ao]);
    Ah2 = *reinterpret_cast<const short8v*>(&MBs[0][6 + kk][ao]);
    Al2 = *reinterpret_cast<const short8v*>(&MBs[1][6 + kk][ao]);
  }

  float n2 = 0.f;
  #pragma unroll
  for (int i = 0; i < 8; ++i) n2 += fn2p[i];
  float c0v = 1.f;

  float sav[2][4], vr[2][4];
  auto vWrite = [&](int bsel) {
    #pragma unroll
    for (int t = 0; t < 2; ++t) {
      ushortT h0 = f2bf(vr[t][0]), h1 = f2bf(vr[t][1]), h2 = f2bf(vr[t][2]), h3 = f2bf(vr[t][3]);
      float r0 = vr[t][0] - bf2f(h0), r1 = vr[t][1] - bf2f(h1);
      float r2 = vr[t][2] - bf2f(h2), r3 = vr[t][3] - bf2f(h3);
      uint2 hw, lw;
      hw.x = (unsigned)h0 | ((unsigned)h1 << 16);
      hw.y = (unsigned)h2 | ((unsigned)h3 << 16);
      lw.x = (unsigned)f2bf(r0) | ((unsigned)f2bf(r1) << 16);
      lw.y = (unsigned)f2bf(r2) | ((unsigned)f2bf(r3) << 16);
      int off = ((fp * 2 + t) * 16 + col) * 40 + st * 16 + kgrp * 4;
      *reinterpret_cast<uint2*>(&vTb[bsel][0][off]) = hw;
      *reinterpret_cast<uint2*>(&vTb[bsel][1][off]) = lw;
    }
  };
  auto mfmaPh = [&](int bsel, short8v AH, short8v AL) {
    if (wact) {
      #pragma unroll
      for (int t = 0; t < 2; ++t) {
        int off = ((fp * 2 + t) * 16 + col) * 40 + kgrp * 8;
        short8v Bh = *reinterpret_cast<const short8v*>(&vTb[bsel][0][off]);
        short8v Bl = *reinterpret_cast<const short8v*>(&vTb[bsel][1][off]);
        Ht[t] = __builtin_amdgcn_mfma_f32_16x16x32_bf16(AH, Bh, Ht[t], 0, 0, 0);
        Ht[t] = __builtin_amdgcn_mfma_f32_16x16x32_bf16(AH, Bl, Ht[t], 0, 0, 0);
        Ht[t] = __builtin_amdgcn_mfma_f32_16x16x32_bf16(AL, Bh, Ht[t], 0, 0, 0);
      }
    }
  };

  int buf = 0;
  for (int layer = 0; layer < 3; ++layer) {
    if (wact) {
      #pragma unroll
      for (int t = 0; t < 2; ++t)
        #pragma unroll
        for (int i = 0; i < 4; ++i) { sav[t][i] = Ht[t][i]; vr[t][i] = 0.f; }
      if (kk == 0) {
        int base = idx * 512 + lane * 8;
        #pragma unroll
        for (int t = 0; t < 2; ++t)
          #pragma unroll
          for (int i = 0; i < 4; ++i) wLx[base + t * 4 + i] = Ht[t][i];
      }
    }
    if (wact && kk == 0) {
      #pragma unroll
      for (int t = 0; t < 2; ++t)
        #pragma unroll
        for (int i = 0; i < 4; ++i) {
          int srow = st * 16 + kgrp * 4 + i;
          vr[t][i] = (srow < 30) ? (eP[t][i] - Ht[t][i]) : 0.f;
        }
      vWrite(buf);
    }
    __syncthreads();
    mfmaPh(buf, Ah0, Al0);
    buf ^= 1;
    if (wact && kk == 0) {
      #pragma unroll
      for (int t = 0; t < 2; ++t)
        #pragma unroll
        for (int i = 0; i < 4; ++i) aT[t][i] += vr[t][i];
    }
    if (wact && kk == 1) {
      int base = idx * 512 + lane * 8;
      #pragma unroll
      for (int t = 0; t < 2; ++t)
        #pragma unroll
        for (int i = 0; i < 4; ++i) {
          int srow = st * 16 + kgrp * 4 + i;
          vr[t][i] = (srow < 30) ? (wLx[base + t * 4 + i] - Ht[t][i]) : 0.f;
        }
      vWrite(buf);
    }
    __syncthreads();
    mfmaPh(buf, Ah1, Al1);
    buf ^= 1;
    if (wact && kk == 1) {
      #pragma unroll
      for (int t = 0; t < 2; ++t)
        #pragma unroll
        for (int i = 0; i < 4; ++i) aT[t][i] += vr[t][i];
    }
    if (wact && kk == 2) {
      #pragma unroll
      for (int t = 0; t < 2; ++t)
        #pragma unroll
        for (int i = 0; i < 4; ++i) {
          int srow = st * 16 + kgrp * 4 + i;
          vr[t][i] = (srow < 30) ? (eP[t][i] - Ht[t][i]) : 0.f;
        }
      vWrite(buf);
    }
    __syncthreads();
    mfmaPh(buf, Ah2, Al2);
    buf ^= 1;
    if (wact && kk == 2) {
      #pragma unroll
      for (int t = 0; t < 2; ++t)
        #pragma unroll
        for (int i = 0; i < 4; ++i) aT[t][i] += vr[t][i];
    }
    float local = 0.f;
    if (wact) {
      #pragma unroll
      for (int t = 0; t < 2; ++t)
        #pragma unroll
        for (int i = 0; i < 4; ++i) {
          int srow = st * 16 + kgrp * 4 + i;
          if (srow < 30) local += vr[t][i] * (sav[t][i] + Ht[t][i]);
        }
    }
    local = wreduce64(local);
    if ((tid & 63) == 0) redL[tid >> 6] = local;
    __syncthreads();
    float tot = n2;
    #pragma unroll
    for (int i = 0; i < 16; ++i) tot += redL[i];
    float fn = fmaxf(sqrtf(tot), 1.f);
    float inv = 1.f / fn;
    n2 = tot * inv * inv;
    c0v *= inv;
    if (wact) {
      #pragma unroll
      for (int t = 0; t < 2; ++t)
        #pragma unroll
        for (int i = 0; i < 4; ++i) { Ht[t][i] *= inv; aT[t][i] *= inv; }
    }
  }

  if (wact) {
    float* dstA = (kk == 0) ? v1L : (kk == 1) ? v2L : v3L;
    #pragma unroll
    for (int t = 0; t < 2; ++t)
      #pragma unroll
      for (int i = 0; i < 4; ++i) {
        int srow = st * 16 + kgrp * 4 + i;
        if (srow < 30) dstA[srow * 68 + (fp * 2 + t) * 16 + col] = aT[t][i];
      }
  }
  if (tid < 64) { uv[tid] = qe1g[(size_t)b * 64 + tid]; siL[tid] = 0.f; }
  __syncthreads();

  int s = tid >> 5;
  bool act = s < 30;
  float* partL = partBuf;
  int k32 = tid & 31;
  for (int stg = 0; stg < 3; ++stg) {
    if (act) {
      float u0 = uv[k32], u1 = uv[k32 + 32];
      float eu1 = e1L[s * 68 + k32] * u0 + e1L[s * 68 + k32 + 32] * u1;
      float eu2 = e2L[s * 68 + k32] * u0 + e2L[s * 68 + k32 + 32] * u1;
      #pragma unroll
      for (int d = 16; d > 0; d >>= 1) {
        eu1 += __shfl_down(eu1, d, 32); eu2 += __shfl_down(eu2, d, 32);
      }
      if (k32 == 0) {
        alf[s]      = eu1 * rqL[stg * 90 + s];
        alf[32 + s] = eu1 * rqL[stg * 90 + 30 + s];
        alf[64 + s] = eu2 * rqL[stg * 90 + 60 + s];
      }
    }
    __syncthreads();
    {
      int p = tid >> 6, f = tid & 63;
      float part = 0.f;
      if (p < 12) {
        int start = (p < 6) ? p * 3 : 18 + (p - 6) * 2;
        int cnt = (p < 6) ? 3 : 2;
        for (int q = 0; q < cnt; ++q) {
          int sp = start + q;
          part += alf[sp] * v1L[sp * 68 + f] + alf[32 + sp] * v2L[sp * 68 + f]
                + alf[64 + sp] * v3L[sp * 68 + f];
        }
      } else {
        int e0 = (p - 12) * 16;
        const float* Gp = Gg + (size_t)stg * 1048576 + (size_t)b * 4096 + (size_t)e0 * 64 + f;
        float F = 0.f;
        #pragma unroll 4
        for (int e = 0; e < 16; ++e) F += uv[e0 + e] * Gp[e * 64];
        part = c0v * F;
      }
      partL[p * 64 + f] = part;
    }
    __syncthreads();
    if (tid < 64) {
      float raw = 0.f;
      #pragma unroll
      for (int p = 0; p < 16; ++p) raw += partL[p * 64 + tid];
      float mean = wreduce64(raw) * (1.f / 64.f);
      float d = raw - mean;
      float var = wreduce64(d * d) * (1.f / 63.f);
      float y = lng[stg * 64 + tid] * d / (sqrtf(var) + 1e-6f) + lnb[stg * 64 + tid];
      siL[tid] += y;
      uv[tid] = y;
    }
    __syncthreads();
  }
  if (tid < 9) {
    float o = 0.f;
    for (int ff = 0; ff < 64; ++ff) o += siL[ff] * Zg[ff * 9 + tid];
    out[(size_t)b * 9 + tid] = o;
  }
}

extern "C" void kernel_launch(void* const* d_in, const int* in_sizes, int n_in,
                              void* d_out, int out_size, void* d_ws, size_t ws_size,
                              hipStream_t stream) {
  const int*   story = (const int*)d_in[0];
  const int*   query = (const int*)d_in[1];
  const float* WE    = (const float*)d_in[2];
  const float* PE    = (const float*)d_in[3];
  const float* ueW1  = (const float*)d_in[4];
  const float* ueb1  = (const float*)d_in[5];
  const float* ueW2  = (const float*)d_in[6];
  const float* ueb2  = (const float*)d_in[7];
  const float* urW1  = (const float*)d_in[8];
  const float* urb1  = (const float*)d_in[9];
  const float* urW2  = (const float*)d_in[10];
  const float* urb2  = (const float*)d_in[11];
  const float* fwm   = (const float*)d_in[12];
  const float* ieW1  = (const float*)d_in[13];
  const float* ieb1  = (const float*)d_in[14];
  const float* ieW2  = (const float*)d_in[15];
  const float* ieb2  = (const float*)d_in[16];
  const float* irW1  = (const float*)d_in[17];
  const float* irb1  = (const float*)d_in[18];
  const float* irW2  = (const float*)d_in[19];
  const float* irb2  = (const float*)d_in[20];
  const float* lng   = (const float*)d_in[21];
  const float* lnb   = (const float*)d_in[22];
  const float* Z     = (const float*)d_in[23];
  float* W = (float*)d_ws;
  float* out = (float*)d_out;

  ushortT* sentB = (ushortT*)(W + OF_SENTB);
  ushortT* qembB = (ushortT*)(W + OF_QEMBB);
  ushortT* W1A   = (ushortT*)(W + OF_W1A);
  ushortT* W2TE  = (ushortT*)(W + OF_W2TE);
  ushortT* W2TR  = (ushortT*)(W + OF_W2TR);
  ushortT* fwmBT = (ushortT*)(W + OF_FWMB);

  prep_k<<<4232, 256, 0, stream>>>(story, query, WE, PE,
      ueW1, urW1, ieW1, irW1, ueW2, urW2, ieW2, irW2, fwm,
      sentB, qembB, W1A, W2TE, W2TR, fwmBT, W + OF_FN2);

  mlpm_k<<<dim3(240, 9), 512, 0, stream>>>(sentB, qembB, W1A,
      ueb1, urb1, ieb1, irb1, W2TE, W2TR, ueb2, urb2, ieb2, irb2,
      W + OF_E1, W + OF_R1, W + OF_QE1, W + OF_QR1);

  pstage_k<<<736, 256, 0, stream>>>(fwmBT, W + OF_E1, W + OF_E1 + 491520,
      W + OF_R1, W + OF_R1 + 245760, W + OF_R1 + 2 * 245760,
      W + OF_QR1, W + OF_QR1 + 8192, W + OF_QR1 + 16384,
      W + OF_PP, W + OF_G);

  scan_k<<<NB, 1024, 0, stream>>>(W + OF_PP, W + OF_G,
      W + OF_E1, W + OF_E1 + 491520,
      W + OF_R1, W + OF_R1 + 245760, W + OF_R1 + 2 * 245760,
      W + OF_QE1, W + OF_QR1, W + OF_QR1 + 8192, W + OF_QR1 + 16384,
      W + OF_FN2, lng, lnb, Z, out);
}

// Round 18
// 117.992 us; speedup vs baseline: 1.0871x; 1.0871x over previous
//
#include <hip/hip_runtime.h>
#include <hip/hip_bf16.h>

// Sizes
#define NB 256
#define NS 30
#define NW 10
#define SYM 128
#define HID 512
#define ENT 64
#define ROLE 32

typedef unsigned short ushortT;
typedef __attribute__((ext_vector_type(8))) short short8v;   // 8 bf16
typedef __attribute__((ext_vector_type(4))) float f32x4;

// Workspace offsets (floats; bf16 arrays use 2 elems per float slot)
static const size_t OF_SENTB = 0;         // 7680*128 bf16 -> 491520 fl
static const size_t OF_QEMBB = 491520;    // 256*128 bf16 -> 16384 fl
static const size_t OF_W1A   = 507904;    // 9*512*128 bf16 -> 294912 fl
static const size_t OF_W2TE  = 802816;    // 3*64*512 bf16 -> 49152 fl
static const size_t OF_W2TR  = 851968;    // 6*32*512 bf16 -> 49152 fl
static const size_t OF_FWMB  = 901120;    // 64*2048 bf16 -> 65536 fl  (fwm^T [f][e*32+r])
static const size_t OF_E1    = 966656;    // 7680*64 x2 (stride 491520)
static const size_t OF_R1    = 1949696;   // 7680*32 x3 (stride 245760)
static const size_t OF_QE1   = 2686976;   // 256*64
static const size_t OF_QR1   = 2703360;   // 256*32 x3 (stride 8192)
static const size_t OF_PP    = 2727936;   // 3 * 7680*64 = 1,474,560
static const size_t OF_FN2   = 4202496;   // 8 partials
static const size_t OF_G     = 4202624;   // 3*256*64*64 = 3,145,728

__device__ __forceinline__ ushortT f2bf(float x) {
  unsigned u = __float_as_uint(x);
  unsigned r = (u + 0x7fffu + ((u >> 16) & 1u)) >> 16;
  return (ushortT)r;
}
__device__ __forceinline__ float bf2f(ushortT h) {
  return __uint_as_float((unsigned)h << 16);
}
__device__ __forceinline__ float ftanh(float x) {
  float t = __expf(2.f * x);
  return 1.f - 2.f * __builtin_amdgcn_rcpf(t + 1.f);
}
__device__ __forceinline__ float dot4(const float4& a, const float4& b) {
  return a.x * b.x + a.y * b.y + a.z * b.z + a.w * b.w;
}
__device__ __forceinline__ float wreduce64(float v) {
  #pragma unroll
  for (int o = 32; o > 0; o >>= 1) v += __shfl_xor(v, o);
  return v;
}

// ---------------- unified prep: embed + all transposes/converts + fnorm partials ----------------
__global__ __launch_bounds__(256) void prep_k(
    const int* __restrict__ story, const int* __restrict__ query,
    const float* __restrict__ WE, const float* __restrict__ PE,
    const float* __restrict__ ueW1, const float* __restrict__ urW1,
    const float* __restrict__ ieW1, const float* __restrict__ irW1,
    const float* __restrict__ ueW2, const float* __restrict__ urW2,
    const float* __restrict__ ieW2, const float* __restrict__ irW2,
    const float* __restrict__ fwm,
    ushortT* __restrict__ sentb, ushortT* __restrict__ qembb,
    ushortT* __restrict__ W1A, ushortT* __restrict__ W2TE,
    ushortT* __restrict__ W2TR, ushortT* __restrict__ fwmBT,
    float* __restrict__ fn2) {
  __shared__ float tl[64 * 65];
  __shared__ float red[4];
  int bx = blockIdx.x, tid = threadIdx.x;
  if (bx < 3968) {
    int row = bx * 2 + (tid >> 7);
    int e = tid & 127;
    const int* idx; ushortT* dst;
    if (row < 7680) { idx = story + (size_t)row * NW; dst = sentb + (size_t)row * SYM; }
    else            { idx = query + (size_t)(row - 7680) * NW; dst = qembb + (size_t)(row - 7680) * SYM; }
    float acc = 0.f;
    #pragma unroll
    for (int w = 0; w < NW; ++w) acc += WE[idx[w] * SYM + e] * PE[w * SYM + e];
    dst[e] = f2bf(acc);
    return;
  }
  bx -= 3968;
  const float* src; ushortT* dst; int R, C, tr0, tc0;
  if (bx < 144) {
    int h = bx >> 4, t = bx & 15;
    src = (h < 2) ? ueW1 + (size_t)h * 65536 : (h < 5) ? urW1 + (size_t)(h - 2) * 65536
        : (h == 5) ? ieW1 : irW1 + (size_t)(h - 6) * 65536;
    dst = W1A + (size_t)h * 65536;
    R = 128; C = 512; tr0 = (t >> 3) * 64; tc0 = (t & 7) * 64;
  } else if (bx < 168) {
    int h = (bx - 144) >> 3, t = (bx - 144) & 7;
    src = (h < 2) ? ueW2 + (size_t)h * 32768 : ieW2;
    dst = W2TE + (size_t)h * 32768;
    R = 512; C = 64; tr0 = t * 64; tc0 = 0;
  } else if (bx < 216) {
    int h = (bx - 168) >> 3, t = (bx - 168) & 7;
    src = (h < 3) ? urW2 + (size_t)h * 16384 : irW2 + (size_t)(h - 3) * 16384;
    dst = W2TR + (size_t)h * 16384;
    R = 512; C = 32; tr0 = t * 64; tc0 = 0;
  } else if (bx < 248) {
    int t = bx - 216;
    src = fwm; dst = fwmBT; R = 2048; C = 64; tr0 = t * 64; tc0 = 0;
  } else {
    int blk = bx - 248;
    const float4* f4 = reinterpret_cast<const float4*>(fwm) + blk * 4096;
    float a = 0.f;
    for (int i = tid; i < 4096; i += 256) {
      float4 v = f4[i];
      a += v.x*v.x + v.y*v.y + v.z*v.z + v.w*v.w;
    }
    a = wreduce64(a);
    if ((tid & 63) == 0) red[tid >> 6] = a;
    __syncthreads();
    if (tid == 0) fn2[blk] = red[0] + red[1] + red[2] + red[3];
    return;
  }
  int TC = (C < 64) ? C : 64;
  int n = 64 * TC;
  for (int i = tid; i < n; i += 256) {
    int r = i / TC, c = i % TC;
    tl[r * 65 + c] = src[(size_t)(tr0 + r) * C + tc0 + c];
  }
  __syncthreads();
  for (int i = tid; i < n; i += 256) {
    int c = i >> 6, r = i & 63;
    dst[(size_t)(tc0 + c) * R + tr0 + r] = f2bf(tl[r * 65 + c]);
  }
}

// ---------------- MFMA fused 2-layer MLP (512 threads / 8 waves, VGPR cap 128) ----------------
__global__ __launch_bounds__(512, 4) void mlpm_k(
    const ushortT* __restrict__ sentB, const ushortT* __restrict__ qembB,
    const ushortT* __restrict__ W1A,
    const float* __restrict__ ueb1, const float* __restrict__ urb1,
    const float* __restrict__ ieb1, const float* __restrict__ irb1,
    const ushortT* __restrict__ W2TE, const ushortT* __restrict__ W2TR,
    const float* __restrict__ ueb2, const float* __restrict__ urb2,
    const float* __restrict__ ieb2, const float* __restrict__ irb2,
    float* __restrict__ E1, float* __restrict__ R1,
    float* __restrict__ QE1, float* __restrict__ QR1) {
  __shared__ __align__(16) ushortT Hl[32 * 520];
  int y = blockIdx.y;
  bool isQ = y >= 5;
  if (isQ && blockIdx.x >= 8) return;
  int r0 = blockIdx.x * 32, tid = threadIdx.x;
  int wave = tid >> 6, lane = tid & 63;
  int lrow = lane & 15;
  int kgrp = lane >> 4;
  const ushortT* Xb = isQ ? qembB : sentB;
  const ushortT* W1h = W1A + (size_t)y * 65536;
  const float* b1 = (y < 2) ? ueb1 + y * 512 : (y < 5) ? urb1 + (y - 2) * 512
                  : (y == 5) ? ieb1 : irb1 + (y - 6) * 512;
  bool isE = (y < 2) || (y == 5);

  int cw = wave * 64;                        // 8 waves x 64 GEMM1 cols

  short8v afr[2][4];
  #pragma unroll
  for (int rt = 0; rt < 2; ++rt) {
    const ushortT* arow = Xb + (size_t)(r0 + rt * 16 + lrow) * 128 + kgrp * 8;
    #pragma unroll
    for (int kt = 0; kt < 4; ++kt)
      afr[rt][kt] = *reinterpret_cast<const short8v*>(arow + kt * 32);
  }

  float bb4[4];
  #pragma unroll
  for (int ct = 0; ct < 4; ++ct) bb4[ct] = b1[cw + ct * 16 + lrow];

  // GEMM1: 4 col-tiles; each B-frag feeds 2 MFMAs (row-tiles)
  #pragma unroll
  for (int ct = 0; ct < 4; ++ct) {
    int c0 = cw + ct * 16;
    const ushortT* bcol = W1h + (size_t)(c0 + lrow) * 128 + kgrp * 8;
    short8v bf0 = *reinterpret_cast<const short8v*>(bcol);
    short8v bf1 = *reinterpret_cast<const short8v*>(bcol + 32);
    short8v bf2 = *reinterpret_cast<const short8v*>(bcol + 64);
    short8v bf3 = *reinterpret_cast<const short8v*>(bcol + 96);
    f32x4 aA[2] = {{0.f,0.f,0.f,0.f},{0.f,0.f,0.f,0.f}};
    f32x4 aB[2] = {{0.f,0.f,0.f,0.f},{0.f,0.f,0.f,0.f}};
    #pragma unroll
    for (int rt = 0; rt < 2; ++rt) {
      aA[rt] = __builtin_amdgcn_mfma_f32_16x16x32_bf16(afr[rt][0], bf0, aA[rt], 0, 0, 0);
      aB[rt] = __builtin_amdgcn_mfma_f32_16x16x32_bf16(afr[rt][1], bf1, aB[rt], 0, 0, 0);
      aA[rt] = __builtin_amdgcn_mfma_f32_16x16x32_bf16(afr[rt][2], bf2, aA[rt], 0, 0, 0);
      aB[rt] = __builtin_amdgcn_mfma_f32_16x16x32_bf16(afr[rt][3], bf3, aB[rt], 0, 0, 0);
    }
    int lcol = c0 + lrow;
    float bb = bb4[ct];
    #pragma unroll
    for (int rt = 0; rt < 2; ++rt)
      #pragma unroll
      for (int i = 0; i < 4; ++i) {
        float hv = ftanh(aA[rt][i] + aB[rt][i] + bb);
        Hl[(rt * 16 + kgrp * 4 + i) * 520 + lcol] = f2bf(hv);
      }
  }
  __syncthreads();

  if (isE) {   // O=64: wave = (row-tile rt, col-quarter cq)
    int slot = (y == 5) ? 2 : y;
    const ushortT* W2h = W2TE + (size_t)slot * 32768;
    const float* b2 = (y == 5) ? ieb2 : ueb2 + y * 64;
    float* Out = (y == 5) ? QE1 : E1 + (size_t)y * 491520;
    int rt = wave >> 2, cq = wave & 3;
    int col = cq * 16 + lrow;
    f32x4 accA = {0.f,0.f,0.f,0.f}, accB = {0.f,0.f,0.f,0.f};
    const ushortT* wc = W2h + (size_t)col * 512;
    #pragma unroll
    for (int kt = 0; kt < 16; kt += 2) {
      int kb0 = kt * 32 + kgrp * 8;
      int kb1 = kb0 + 32;
      short8v a0 = *reinterpret_cast<const short8v*>(&Hl[(rt * 16 + lrow) * 520 + kb0]);
      short8v a1 = *reinterpret_cast<const short8v*>(&Hl[(rt * 16 + lrow) * 520 + kb1]);
      short8v b0 = *reinterpret_cast<const short8v*>(wc + kb0);
      short8v b1v = *reinterpret_cast<const short8v*>(wc + kb1);
      accA = __builtin_amdgcn_mfma_f32_16x16x32_bf16(a0, b0, accA, 0, 0, 0);
      accB = __builtin_amdgcn_mfma_f32_16x16x32_bf16(a1, b1v, accB, 0, 0, 0);
    }
    float bb = b2[col];
    #pragma unroll
    for (int i = 0; i < 4; ++i) {
      int grow = r0 + rt * 16 + kgrp * 4 + i;
      Out[(size_t)grow * 64 + col] = ftanh(accA[i] + accB[i] + bb);
    }
  } else {     // O=32: waves with cq<2 active
    int slot = (y < 5) ? (y - 2) : (3 + y - 6);
    const ushortT* W2h = W2TR + (size_t)slot * 16384;
    const float* b2 = (y < 5) ? urb2 + (y - 2) * 32 : irb2 + (y - 6) * 32;
    float* Out = (y < 5) ? R1 + (size_t)(y - 2) * 245760 : QR1 + (size_t)(y - 6) * 8192;
    int rt = wave >> 2, cq = wave & 3;
    if (cq < 2) {
      int col = cq * 16 + lrow;
      f32x4 accA = {0.f, 0.f, 0.f, 0.f}, accB = {0.f, 0.f, 0.f, 0.f};
      const ushortT* wc = W2h + (size_t)col * 512;
      #pragma unroll
      for (int kt = 0; kt < 16; kt += 2) {
        int kb0 = kt * 32 + kgrp * 8;
        int kb1 = kb0 + 32;
        short8v a0 = *reinterpret_cast<const short8v*>(&Hl[(rt * 16 + lrow) * 520 + kb0]);
        short8v a1 = *reinterpret_cast<const short8v*>(&Hl[(rt * 16 + lrow) * 520 + kb1]);
        short8v b0 = *reinterpret_cast<const short8v*>(wc + kb0);
        short8v b1v = *reinterpret_cast<const short8v*>(wc + kb1);
        accA = __builtin_amdgcn_mfma_f32_16x16x32_bf16(a0, b0, accA, 0, 0, 0);
        accB = __builtin_amdgcn_mfma_f32_16x16x32_bf16(a1, b1v, accB, 0, 0, 0);
      }
      float bb = b2[col];
      #pragma unroll
      for (int i = 0; i < 4; ++i) {
        int grow = r0 + rt * 16 + kgrp * 4 + i;
        Out[(size_t)grow * 32 + col] = ftanh(accA[i] + accB[i] + bb);
      }
    }
  }
}

// ---------------- MFMA P-stage (bx<480) + G-stage (bx>=480) ----------------
__global__ __launch_bounds__(256) void pstage_k(const ushortT* __restrict__ fwmBT,
    const float* __restrict__ e1g, const float* __restrict__ e2g,
    const float* __restrict__ r1g, const float* __restrict__ r2g, const float* __restrict__ r3g,
    const float* __restrict__ qr1g, const float* __restrict__ qr2g, const float* __restrict__ qr3g,
    float* __restrict__ Pp, float* __restrict__ Gg) {
  __shared__ __align__(16) float e1t[16 * 68], e2t[16 * 68];
  int bx = blockIdx.x, tid = threadIdx.x;
  int wave = tid >> 6, lane = tid & 63;
  int c = lane & 15, kg = lane >> 4;
  int f0 = wave * 16;
  const f32x4 zero = {0,0,0,0};

  if (bx >= 480) {
    int b = bx - 480;
    short8v qa = {0,0,0,0,0,0,0,0};
    if (c < 3) {
      const float* qr = ((c == 0) ? qr1g : (c == 1) ? qr2g : qr3g) + (size_t)b * 32 + kg * 8;
      ushortT* p = (ushortT*)&qa;
      #pragma unroll
      for (int j = 0; j < 8; ++j) p[j] = f2bf(qr[j]);
    }
    const ushortT* bbase = fwmBT + (size_t)(f0 + c) * 2048 + kg * 8;
    float* g0 = Gg + (size_t)b * 4096 + f0 + c;
    for (int e = 0; e < 64; ++e) {
      short8v B = *reinterpret_cast<const short8v*>(bbase + (size_t)e * 32);
      f32x4 T = __builtin_amdgcn_mfma_f32_16x16x32_bf16(qa, B, zero, 0, 0, 0);
      if (kg == 0) {
        g0[e * 64]           = T[0];
        g0[1048576 + e * 64] = T[1];
        g0[2097152 + e * 64] = T[2];
      }
    }
    return;
  }

  int rb = bx;
  {
    int row = tid >> 4, c4 = tid & 15;
    float4 v1 = *reinterpret_cast<const float4*>(e1g + ((size_t)rb * 16 + row) * 64 + c4 * 4);
    float4 v2 = *reinterpret_cast<const float4*>(e2g + ((size_t)rb * 16 + row) * 64 + c4 * 4);
    *reinterpret_cast<float4*>(&e1t[row * 68 + c4 * 4]) = v1;
    *reinterpret_cast<float4*>(&e2t[row * 68 + c4 * 4]) = v2;
  }
  size_t rbase = ((size_t)rb * 16 + c) * 32 + kg * 8;
  short8v rA, rB, rC;
  {
    float4 x0 = *reinterpret_cast<const float4*>(r1g + rbase);
    float4 x1 = *reinterpret_cast<const float4*>(r1g + rbase + 4);
    ushortT* p = (ushortT*)&rA;
    p[0]=f2bf(x0.x); p[1]=f2bf(x0.y); p[2]=f2bf(x0.z); p[3]=f2bf(x0.w);
    p[4]=f2bf(x1.x); p[5]=f2bf(x1.y); p[6]=f2bf(x1.z); p[7]=f2bf(x1.w);
    x0 = *reinterpret_cast<const float4*>(r2g + rbase);
    x1 = *reinterpret_cast<const float4*>(r2g + rbase + 4);
    p = (ushortT*)&rB;
    p[0]=f2bf(x0.x); p[1]=f2bf(x0.y); p[2]=f2bf(x0.z); p[3]=f2bf(x0.w);
    p[4]=f2bf(x1.x); p[5]=f2bf(x1.y); p[6]=f2bf(x1.z); p[7]=f2bf(x1.w);
    x0 = *reinterpret_cast<const float4*>(r3g + rbase);
    x1 = *reinterpret_cast<const float4*>(r3g + rbase + 4);
    p = (ushortT*)&rC;
    p[0]=f2bf(x0.x); p[1]=f2bf(x0.y); p[2]=f2bf(x0.z); p[3]=f2bf(x0.w);
    p[4]=f2bf(x1.x); p[5]=f2bf(x1.y); p[6]=f2bf(x1.z); p[7]=f2bf(x1.w);
  }
  __syncthreads();
  const ushortT* bbase = fwmBT + (size_t)(f0 + c) * 2048 + kg * 8;
  f32x4 P1 = {0,0,0,0}, P2 = {0,0,0,0}, P3 = {0,0,0,0};
  int r0 = kg * 4;
  for (int e4 = 0; e4 < 16; ++e4) {
    float4 ea[4], eb[4];
    #pragma unroll
    for (int i = 0; i < 4; ++i) {
      ea[i] = *reinterpret_cast<const float4*>(&e1t[(r0 + i) * 68 + e4 * 4]);
      eb[i] = *reinterpret_cast<const float4*>(&e2t[(r0 + i) * 68 + e4 * 4]);
    }
    #pragma unroll
    for (int sub = 0; sub < 4; ++sub) {
      int e = e4 * 4 + sub;
      short8v B = *reinterpret_cast<const short8v*>(bbase + (size_t)e * 32);
      f32x4 T1 = __builtin_amdgcn_mfma_f32_16x16x32_bf16(rA, B, zero, 0, 0, 0);
      f32x4 T2 = __builtin_amdgcn_mfma_f32_16x16x32_bf16(rB, B, zero, 0, 0, 0);
      f32x4 T3 = __builtin_amdgcn_mfma_f32_16x16x32_bf16(rC, B, zero, 0, 0, 0);
      #pragma unroll
      for (int i = 0; i < 4; ++i) {
        float e1v = reinterpret_cast<const float*>(&ea[i])[sub];
        float e2v = reinterpret_cast<const float*>(&eb[i])[sub];
        P1[i] += e1v * T1[i];
        P2[i] += e1v * T2[i];
        P3[i] += e2v * T3[i];
      }
    }
  }
  #pragma unroll
  for (int i = 0; i < 4; ++i) {
    size_t row = (size_t)rb * 16 + kg * 4 + i;
    Pp[row * 64 + f0 + c]               = P1[i];
    Pp[491520 + row * 64 + f0 + c]      = P2[i];
    Pp[2 * 491520 + row * 64 + f0 + c]  = P3[i];
  }
}

// ---------------- scan: gram(bf16 hi/lo M) + MFMA propagation + inference ----------------
__global__ __launch_bounds__(1024) void scan_k(
    const float* __restrict__ Pp, const float* __restrict__ Gg,
    const float* __restrict__ e1g, const float* __restrict__ e2g,
    const float* __restrict__ r1g, const float* __restrict__ r2g, const float* __restrict__ r3g,
    const float* __restrict__ qe1g, const float* __restrict__ qr1g, const float* __restrict__ qr2g,
    const float* __restrict__ qr3g, const float* __restrict__ fn2p,
    const float* __restrict__ lng, const float* __restrict__ lnb, const float* __restrict__ Zg,
    float* __restrict__ out) {
  __shared__ __align__(16) ushortT MBs[2][9][1280];     // [hi/lo][ph*3+kk][row*40+col] bf16 M
  __shared__ __align__(16) ushortT vTb[2][2][2560];     // [buf][hi/lo][f*40+sp]
  __shared__ float wLx[2048];                            // w relay
  __shared__ float partBuf[1024];
  __shared__ __align__(16) float e1L[2040], e2L[2040];  // [30][68]
  __shared__ __align__(16) float v1L[2040], v2L[2040], v3L[2040];
  __shared__ __align__(16) float r1L[1080], r2L[1080], r3L[1080];  // [30][36]
  __shared__ float uv[64], qv[96], alf[96], siL[64], rqL[272];
  __shared__ float redL[16];
  int b = blockIdx.x, tid = threadIdx.x;
  int wave = tid >> 6, lane = tid & 63;
  int col = lane & 15, kgrp = lane >> 4;
  bool wact = wave < 12;
  int kk = wave >> 2, idx = wave & 3, st = idx >> 1, fp = idx & 1;

  // ---- staging ----
  for (int i = tid; i < 1680; i += 1024) {
    if (i < 480) {
      int ss = i >> 4, c4 = i & 15;
      *reinterpret_cast<float4*>(&e1L[ss * 68 + c4 * 4]) =
          *reinterpret_cast<const float4*>(e1g + (size_t)b * 1920 + i * 4);
    } else if (i < 960) {
      int j = i - 480;
      int ss = j >> 4, c4 = j & 15;
      *reinterpret_cast<float4*>(&e2L[ss * 68 + c4 * 4]) =
          *reinterpret_cast<const float4*>(e2g + (size_t)b * 1920 + j * 4);
    } else {
      int j = i - 960;
      int which = j / 240, jj = j - which * 240;
      int ss = jj >> 3, c4 = jj & 7;
      float* dstL = (which == 0) ? r1L : (which == 1) ? r2L : r3L;
      const float* srcG = (which == 0) ? r1g : (which == 1) ? r2g : r3g;
      *reinterpret_cast<float4*>(&dstL[ss * 36 + c4 * 4]) =
          *reinterpret_cast<const float4*>(srcG + (size_t)b * 960 + jj * 4);
    }
  }
  if (tid >= 128 && tid < 224) {
    int t = tid - 128, sst = t >> 5, k = t & 31;
    const float* qrg = (sst == 0) ? qr1g : ((sst == 1) ? qr2g : qr3g);
    qv[t] = qrg[(size_t)b * 32 + k];
  }
  for (int i = tid; i < 7200; i += 1024) {
    int m = i / 400, rr = i - m * 400;
    int hl = m / 9, mat = m - hl * 9;
    int r, c;
    if (rr < 320) { r = rr / 10; c = 30 + rr % 10; }
    else { int q = rr - 320; r = 30 + q / 40; c = q % 40; }
    MBs[hl][mat][r * 40 + c] = 0;
  }
  f32x4 Ht[2] = {{0.f,0.f,0.f,0.f},{0.f,0.f,0.f,0.f}};
  float aT[2][4] = {{0,0,0,0},{0,0,0,0}};
  if (wact) {
    #pragma unroll
    for (int t = 0; t < 2; ++t)
      #pragma unroll
      for (int i = 0; i < 4; ++i) {
        int srow = st * 16 + kgrp * 4 + i;
        int f = (fp * 2 + t) * 16 + col;
        Ht[t][i] = (srow < 30) ? Pp[(size_t)kk * 491520 + (size_t)b * 1920 + srow * 64 + f] : 0.f;
      }
  }
  __syncthreads();

  // ---- gram -> bf16 hi/lo M ; rqL ----
  if (tid < 900) {
    int si = tid / 30, sj = tid - si * 30;
    float g11 = 0, g12 = 0, g21 = 0, g22 = 0;
    {
      const float4* A1 = reinterpret_cast<const float4*>(&e1L[si * 68]);
      const float4* A2 = reinterpret_cast<const float4*>(&e2L[si * 68]);
      const float4* C1 = reinterpret_cast<const float4*>(&e1L[sj * 68]);
      const float4* C2 = reinterpret_cast<const float4*>(&e2L[sj * 68]);
      #pragma unroll 4
      for (int i = 0; i < 16; ++i) {
        float4 a1v = A1[i], a2v = A2[i], c1v = C1[i], c2v = C2[i];
        g11 += dot4(a1v, c1v); g12 += dot4(a1v, c2v);
        g21 += dot4(a2v, c1v); g22 += dot4(a2v, c2v);
      }
    }
    float R11=0,R12=0,R13=0,R21=0,R22=0,R23=0,R31=0,R32=0,R33=0;
    {
      const float4* X1 = reinterpret_cast<const float4*>(&r1L[si * 36]);
      const float4* X2 = reinterpret_cast<const float4*>(&r2L[si * 36]);
      const float4* X3 = reinterpret_cast<const float4*>(&r3L[si * 36]);
      const float4* Y1 = reinterpret_cast<const float4*>(&r1L[sj * 36]);
      const float4* Y2 = reinterpret_cast<const float4*>(&r2L[sj * 36]);
      const float4* Y3 = reinterpret_cast<const float4*>(&r3L[sj * 36]);
      #pragma unroll 4
      for (int i = 0; i < 8; ++i) {
        float4 x1 = X1[i], x2 = X2[i], x3 = X3[i];
        float4 y1 = Y1[i], y2 = Y2[i], y3 = Y3[i];
        R11 += dot4(x1, y1); R12 += dot4(x1, y2); R13 += dot4(x1, y3);
        R21 += dot4(x2, y1); R22 += dot4(x2, y2); R23 += dot4(x2, y3);
        R31 += dot4(x3, y1); R32 += dot4(x3, y2); R33 += dot4(x3, y3);
      }
    }
    float vals[9];
    vals[0] = g11 * R11; vals[1] = g11 * R21; vals[2] = g21 * R31;
    vals[3] = g11 * R12; vals[4] = g11 * R22; vals[5] = g21 * R32;
    vals[6] = g12 * R13; vals[7] = g12 * R23; vals[8] = g22 * R33;
    int o = si * 40 + sj;
    #pragma unroll
    for (int m = 0; m < 9; ++m) {
      ushortT hi = f2bf(vals[m]);
      float res = vals[m] - bf2f(hi);
      MBs[0][m][o] = hi;
      MBs[1][m][o] = f2bf(res);
    }
  } else {
    #pragma unroll
    for (int ch = 0; ch < 3; ++ch) {
      int t = (tid - 900) + ch * 124;
      if (t < 270) {
        int sst = t / 90, rem = t - sst * 90;
        int k = rem / 30, s2 = rem - k * 30;
        const float* rL = (k == 0) ? r1L : (k == 1) ? r2L : r3L;
        const float* qp = qv + sst * 32;
        float a = 0.f;
        #pragma unroll 8
        for (int r = 0; r < 32; ++r) a += rL[s2 * 36 + r] * qp[r];
        rqL[sst * 90 + k * 30 + s2] = a;
      }
    }
  }
  float eP[2][4] = {{0,0,0,0},{0,0,0,0}};
  if (wact && kk != 1) {
    const float* eSrc = (kk == 0) ? e2L : e1L;
    #pragma unroll
    for (int t = 0; t < 2; ++t)
      #pragma unroll
      for (int i = 0; i < 4; ++i) {
        int srow = st * 16 + kgrp * 4 + i;
        if (srow < 30) eP[t][i] = eSrc[srow * 68 + (fp * 2 + t) * 16 + col];
      }
  }
  __syncthreads();

  short8v Ah0, Al0, Ah1, Al1, Ah2, Al2;
  if (wact) {
    int ao = (st * 16 + col) * 40 + kgrp * 8;
    Ah0 = *reinterpret_cast<const short8v*>(&MBs[0][kk][ao]);
    Al0 = *reinterpret_cast<const short8v*>(&MBs[1][kk][ao]);
    Ah1 = *reinterpret_cast<const short8v*>(&MBs[0][3 + kk][ao]);
    Al1 = *reinterpret_cast<const short8v*>(&MBs[1][3 + kk][ao]);
    Ah2 = *reinterpret_cast<const short8v*>(&MBs[0][6 + kk][ao]);
    Al2 = *reinterpret_cast<const short8v*>(&MBs[1][6 + kk][ao]);
  }

  float n2 = 0.f;
  #pragma unroll
  for (int i = 0; i < 8; ++i) n2 += fn2p[i];
  float c0v = 1.f;

  float sav[2][4], vr[2][4];
  auto vWrite = [&](int bsel) {
    #pragma unroll
    for (int t = 0; t < 2; ++t) {
      ushortT h0 = f2bf(vr[t][0]), h1 = f2bf(vr[t][1]), h2 = f2bf(vr[t][2]), h3 = f2bf(vr[t][3]);
      float r0 = vr[t][0] - bf2f(h0), r1 = vr[t][1] - bf2f(h1);
      float r2 = vr[t][2] - bf2f(h2), r3 = vr[t][3] - bf2f(h3);
      uint2 hw, lw;
      hw.x = (unsigned)h0 | ((unsigned)h1 << 16);
      hw.y = (unsigned)h2 | ((unsigned)h3 << 16);
      lw.x = (unsigned)f2bf(r0) | ((unsigned)f2bf(r1) << 16);
      lw.y = (unsigned)f2bf(r2) | ((unsigned)f2bf(r3) << 16);
      int off = ((fp * 2 + t) * 16 + col) * 40 + st * 16 + kgrp * 4;
      *reinterpret_cast<uint2*>(&vTb[bsel][0][off]) = hw;
      *reinterpret_cast<uint2*>(&vTb[bsel][1][off]) = lw;
    }
  };
  auto mfmaPh = [&](int bsel, short8v AH, short8v AL) {
    if (wact) {
      #pragma unroll
      for (int t = 0; t < 2; ++t) {
        int off = ((fp * 2 + t) * 16 + col) * 40 + kgrp * 8;
        short8v Bh = *reinterpret_cast<const short8v*>(&vTb[bsel][0][off]);
        short8v Bl = *reinterpret_cast<const short8v*>(&vTb[bsel][1][off]);
        Ht[t] = __builtin_amdgcn_mfma_f32_16x16x32_bf16(AH, Bh, Ht[t], 0, 0, 0);
        Ht[t] = __builtin_amdgcn_mfma_f32_16x16x32_bf16(AH, Bl, Ht[t], 0, 0, 0);
        Ht[t] = __builtin_amdgcn_mfma_f32_16x16x32_bf16(AL, Bh, Ht[t], 0, 0, 0);
      }
    }
  };

  int buf = 0;
  for (int layer = 0; layer < 3; ++layer) {
    if (wact) {
      #pragma unroll
      for (int t = 0; t < 2; ++t)
        #pragma unroll
        for (int i = 0; i < 4; ++i) { sav[t][i] = Ht[t][i]; vr[t][i] = 0.f; }
      if (kk == 0) {
        int base = idx * 512 + lane * 8;
        #pragma unroll
        for (int t = 0; t < 2; ++t)
          #pragma unroll
          for (int i = 0; i < 4; ++i) wLx[base + t * 4 + i] = Ht[t][i];
      }
    }
    if (wact && kk == 0) {
      #pragma unroll
      for (int t = 0; t < 2; ++t)
        #pragma unroll
        for (int i = 0; i < 4; ++i) {
          int srow = st * 16 + kgrp * 4 + i;
          vr[t][i] = (srow < 30) ? (eP[t][i] - Ht[t][i]) : 0.f;
        }
      vWrite(buf);
    }
    __syncthreads();
    mfmaPh(buf, Ah0, Al0);
    buf ^= 1;
    if (wact && kk == 0) {
      #pragma unroll
      for (int t = 0; t < 2; ++t)
        #pragma unroll
        for (int i = 0; i < 4; ++i) aT[t][i] += vr[t][i];
    }
    if (wact && kk == 1) {
      int base = idx * 512 + lane * 8;
      #pragma unroll
      for (int t = 0; t < 2; ++t)
        #pragma unroll
        for (int i = 0; i < 4; ++i) {
          int srow = st * 16 + kgrp * 4 + i;
          vr[t][i] = (srow < 30) ? (wLx[base + t * 4 + i] - Ht[t][i]) : 0.f;
        }
      vWrite(buf);
    }
    __syncthreads();
    mfmaPh(buf, Ah1, Al1);
    buf ^= 1;
    if (wact && kk == 1) {
      #pragma unroll
      for (int t = 0; t < 2; ++t)
        #pragma unroll
        for (int i = 0; i < 4; ++i) aT[t][i] += vr[t][i];
    }
    if (wact && kk == 2) {
      #pragma unroll
      for (int t = 0; t < 2; ++t)
        #pragma unroll
        for (int i = 0; i < 4; ++i) {
          int srow = st * 16 + kgrp * 4 + i;
          vr[t][i] = (srow < 30) ? (eP[t][i] - Ht[t][i]) : 0.f;
        }
      vWrite(buf);
    }
    __syncthreads();
    mfmaPh(buf, Ah2, Al2);
    buf ^= 1;
    if (wact && kk == 2) {
      #pragma unroll
      for (int t = 0; t < 2; ++t)
        #pragma unroll
        for (int i = 0; i < 4; ++i) aT[t][i] += vr[t][i];
    }
    float local = 0.f;
    if (wact) {
      #pragma unroll
      for (int t = 0; t < 2; ++t)
        #pragma unroll
        for (int i = 0; i < 4; ++i) {
          int srow = st * 16 + kgrp * 4 + i;
          if (srow < 30) local += vr[t][i] * (sav[t][i] + Ht[t][i]);
        }
    }
    local = wreduce64(local);
    if ((tid & 63) == 0) redL[tid >> 6] = local;
    __syncthreads();
    float tot = n2;
    #pragma unroll
    for (int i = 0; i < 16; ++i) tot += redL[i];
    float fn = fmaxf(sqrtf(tot), 1.f);
    float inv = 1.f / fn;
    n2 = tot * inv * inv;
    c0v *= inv;
    if (wact) {
      #pragma unroll
      for (int t = 0; t < 2; ++t)
        #pragma unroll
        for (int i = 0; i < 4; ++i) { Ht[t][i] *= inv; aT[t][i] *= inv; }
    }
  }

  if (wact) {
    float* dstA = (kk == 0) ? v1L : (kk == 1) ? v2L : v3L;
    #pragma unroll
    for (int t = 0; t < 2; ++t)
      #pragma unroll
      for (int i = 0; i < 4; ++i) {
        int srow = st * 16 + kgrp * 4 + i;
        if (srow < 30) dstA[srow * 68 + (fp * 2 + t) * 16 + col] = aT[t][i];
      }
  }
  if (tid < 64) { uv[tid] = qe1g[(size_t)b * 64 + tid]; siL[tid] = 0.f; }
  __syncthreads();

  int s = tid >> 5;
  bool act = s < 30;
  float* partL = partBuf;
  int k32 = tid & 31;
  for (int stg = 0; stg < 3; ++stg) {
    if (act) {
      float u0 = uv[k32], u1 = uv[k32 + 32];
      float eu1 = e1L[s * 68 + k32] * u0 + e1L[s * 68 + k32 + 32] * u1;
      float eu2 = e2L[s * 68 + k32] * u0 + e2L[s * 68 + k32 + 32] * u1;
      #pragma unroll
      for (int d = 16; d > 0; d >>= 1) {
        eu1 += __shfl_down(eu1, d, 32); eu2 += __shfl_down(eu2, d, 32);
      }
      if (k32 == 0) {
        alf[s]      = eu1 * rqL[stg * 90 + s];
        alf[32 + s] = eu1 * rqL[stg * 90 + 30 + s];
        alf[64 + s] = eu2 * rqL[stg * 90 + 60 + s];
      }
    }
    __syncthreads();
    {
      int p = tid >> 6, f = tid & 63;
      float part = 0.f;
      if (p < 12) {
        int start = (p < 6) ? p * 3 : 18 + (p - 6) * 2;
        int cnt = (p < 6) ? 3 : 2;
        for (int q = 0; q < cnt; ++q) {
          int sp = start + q;
          part += alf[sp] * v1L[sp * 68 + f] + alf[32 + sp] * v2L[sp * 68 + f]
                + alf[64 + sp] * v3L[sp * 68 + f];
        }
      } else {
        int e0 = (p - 12) * 16;
        const float* Gp = Gg + (size_t)stg * 1048576 + (size_t)b * 4096 + (size_t)e0 * 64 + f;
        float F = 0.f;
        #pragma unroll 4
        for (int e = 0; e < 16; ++e) F += uv[e0 + e] * Gp[e * 64];
        part = c0v * F;
      }
      partL[p * 64 + f] = part;
    }
    __syncthreads();
    if (tid < 64) {
      float raw = 0.f;
      #pragma unroll
      for (int p = 0; p < 16; ++p) raw += partL[p * 64 + tid];
      float mean = wreduce64(raw) * (1.f / 64.f);
      float d = raw - mean;
      float var = wreduce64(d * d) * (1.f / 63.f);
      float y = lng[stg * 64 + tid] * d / (sqrtf(var) + 1e-6f) + lnb[stg * 64 + tid];
      siL[tid] += y;
      uv[tid] = y;
    }
    __syncthreads();
  }
  if (tid < 9) {
    float o = 0.f;
    for (int ff = 0; ff < 64; ++ff) o += siL[ff] * Zg[ff * 9 + tid];
    out[(size_t)b * 9 + tid] = o;
  }
}

extern "C" void kernel_launch(void* const* d_in, const int* in_sizes, int n_in,
                              void* d_out, int out_size, void* d_ws, size_t ws_size,
                              hipStream_t stream) {
  const int*   story = (const int*)d_in[0];
  const int*   query = (const int*)d_in[1];
  const float* WE    = (const float*)d_in[2];
  const float* PE    = (const float*)d_in[3];
  const float* ueW1  = (const float*)d_in[4];
  const float* ueb1  = (const float*)d_in[5];
  const float* ueW2  = (const float*)d_in[6];
  const float* ueb2  = (const float*)d_in[7];
  const float* urW1  = (const float*)d_in[8];
  const float* urb1  = (const float*)d_in[9];
  const float* urW2  = (const float*)d_in[10];
  const float* urb2  = (const float*)d_in[11];
  const float* fwm   = (const float*)d_in[12];
  const float* ieW1  = (const float*)d_in[13];
  const float* ieb1  = (const float*)d_in[14];
  const float* ieW2  = (const float*)d_in[15];
  const float* ieb2  = (const float*)d_in[16];
  const float* irW1  = (const float*)d_in[17];
  const float* irb1  = (const float*)d_in[18];
  const float* irW2  = (const float*)d_in[19];
  const float* irb2  = (const float*)d_in[20];
  const float* lng   = (const float*)d_in[21];
  const float* lnb   = (const float*)d_in[22];
  const float* Z     = (const float*)d_in[23];
  float* W = (float*)d_ws;
  float* out = (float*)d_out;

  ushortT* sentB = (ushortT*)(W + OF_SENTB);
  ushortT* qembB = (ushortT*)(W + OF_QEMBB);
  ushortT* W1A   = (ushortT*)(W + OF_W1A);
  ushortT* W2TE  = (ushortT*)(W + OF_W2TE);
  ushortT* W2TR  = (ushortT*)(W + OF_W2TR);
  ushortT* fwmBT = (ushortT*)(W + OF_FWMB);

  prep_k<<<4232, 256, 0, stream>>>(story, query, WE, PE,
      ueW1, urW1, ieW1, irW1, ueW2, urW2, ieW2, irW2, fwm,
      sentB, qembB, W1A, W2TE, W2TR, fwmBT, W + OF_FN2);

  mlpm_k<<<dim3(240, 9), 512, 0, stream>>>(sentB, qembB, W1A,
      ueb1, urb1, ieb1, irb1, W2TE, W2TR, ueb2, urb2, ieb2, irb2,
      W + OF_E1, W + OF_R1, W + OF_QE1, W + OF_QR1);

  pstage_k<<<736, 256, 0, stream>>>(fwmBT, W + OF_E1, W + OF_E1 + 491520,
      W + OF_R1, W + OF_R1 + 245760, W + OF_R1 + 2 * 245760,
      W + OF_QR1, W + OF_QR1 + 8192, W + OF_QR1 + 16384,
      W + OF_PP, W + OF_G);

  scan_k<<<NB, 1024, 0, stream>>>(W + OF_PP, W + OF_G,
      W + OF_E1, W + OF_E1 + 491520,
      W + OF_R1, W + OF_R1 + 245760, W + OF_R1 + 2 * 245760,
      W + OF_QE1, W + OF_QR1, W + OF_QR1 + 8192, W + OF_QR1 + 16384,
      W + OF_FN2, lng, lnb, Z, out);
}

// Round 19
// 115.208 us; speedup vs baseline: 1.1133x; 1.0242x over previous
//
#include <hip/hip_runtime.h>
#include <hip/hip_bf16.h>

// Sizes
#define NB 256
#define NS 30
#define NW 10
#define SYM 128
#define HID 512
#define ENT 64
#define ROLE 32

typedef unsigned short ushortT;
typedef __attribute__((ext_vector_type(8))) short short8v;   // 8 bf16
typedef __attribute__((ext_vector_type(4))) float f32x4;

// Workspace offsets (floats; bf16 arrays use 2 elems per float slot)
static const size_t OF_SENTB = 0;         // 7680*128 bf16 -> 491520 fl
static const size_t OF_QEMBB = 491520;    // 256*128 bf16 -> 16384 fl
static const size_t OF_W1A   = 507904;    // 9*512*128 bf16 -> 294912 fl
static const size_t OF_W2TE  = 802816;    // 3*64*512 bf16 -> 49152 fl
static const size_t OF_W2TR  = 851968;    // 6*32*512 bf16 -> 49152 fl
static const size_t OF_FWMB  = 901120;    // 64*2048 bf16 -> 65536 fl  (fwm^T [f][e*32+r])
static const size_t OF_E1    = 966656;    // 7680*64 x2 (stride 491520)
static const size_t OF_R1    = 1949696;   // 7680*32 x3 (stride 245760)
static const size_t OF_QE1   = 2686976;   // 256*64
static const size_t OF_QR1   = 2703360;   // 256*32 x3 (stride 8192)
static const size_t OF_PP    = 2727936;   // 3 * 7680*64 = 1,474,560
static const size_t OF_FN2   = 4202496;   // 8 partials
static const size_t OF_G     = 4202624;   // 3*256*64*64 = 3,145,728

__device__ __forceinline__ ushortT f2bf(float x) {
  unsigned u = __float_as_uint(x);
  unsigned r = (u + 0x7fffu + ((u >> 16) & 1u)) >> 16;
  return (ushortT)r;
}
__device__ __forceinline__ float bf2f(ushortT h) {
  return __uint_as_float((unsigned)h << 16);
}
__device__ __forceinline__ float ftanh(float x) {
  float t = __expf(2.f * x);
  return 1.f - 2.f * __builtin_amdgcn_rcpf(t + 1.f);
}
__device__ __forceinline__ float dot4(const float4& a, const float4& b) {
  return a.x * b.x + a.y * b.y + a.z * b.z + a.w * b.w;
}
__device__ __forceinline__ float wreduce64(float v) {
  #pragma unroll
  for (int o = 32; o > 0; o >>= 1) v += __shfl_xor(v, o);
  return v;
}

// ---------------- unified prep: embed + all transposes/converts + fnorm partials ----------------
__global__ __launch_bounds__(256) void prep_k(
    const int* __restrict__ story, const int* __restrict__ query,
    const float* __restrict__ WE, const float* __restrict__ PE,
    const float* __restrict__ ueW1, const float* __restrict__ urW1,
    const float* __restrict__ ieW1, const float* __restrict__ irW1,
    const float* __restrict__ ueW2, const float* __restrict__ urW2,
    const float* __restrict__ ieW2, const float* __restrict__ irW2,
    const float* __restrict__ fwm,
    ushortT* __restrict__ sentb, ushortT* __restrict__ qembb,
    ushortT* __restrict__ W1A, ushortT* __restrict__ W2TE,
    ushortT* __restrict__ W2TR, ushortT* __restrict__ fwmBT,
    float* __restrict__ fn2) {
  __shared__ float tl[64 * 65];
  __shared__ float red[4];
  int bx = blockIdx.x, tid = threadIdx.x;
  if (bx < 3968) {
    int row = bx * 2 + (tid >> 7);
    int e = tid & 127;
    const int* idx; ushortT* dst;
    if (row < 7680) { idx = story + (size_t)row * NW; dst = sentb + (size_t)row * SYM; }
    else            { idx = query + (size_t)(row - 7680) * NW; dst = qembb + (size_t)(row - 7680) * SYM; }
    float acc = 0.f;
    #pragma unroll
    for (int w = 0; w < NW; ++w) acc += WE[idx[w] * SYM + e] * PE[w * SYM + e];
    dst[e] = f2bf(acc);
    return;
  }
  bx -= 3968;
  const float* src; ushortT* dst; int R, C, tr0, tc0;
  if (bx < 144) {
    int h = bx >> 4, t = bx & 15;
    src = (h < 2) ? ueW1 + (size_t)h * 65536 : (h < 5) ? urW1 + (size_t)(h - 2) * 65536
        : (h == 5) ? ieW1 : irW1 + (size_t)(h - 6) * 65536;
    dst = W1A + (size_t)h * 65536;
    R = 128; C = 512; tr0 = (t >> 3) * 64; tc0 = (t & 7) * 64;
  } else if (bx < 168) {
    int h = (bx - 144) >> 3, t = (bx - 144) & 7;
    src = (h < 2) ? ueW2 + (size_t)h * 32768 : ieW2;
    dst = W2TE + (size_t)h * 32768;
    R = 512; C = 64; tr0 = t * 64; tc0 = 0;
  } else if (bx < 216) {
    int h = (bx - 168) >> 3, t = (bx - 168) & 7;
    src = (h < 3) ? urW2 + (size_t)h * 16384 : irW2 + (size_t)(h - 3) * 16384;
    dst = W2TR + (size_t)h * 16384;
    R = 512; C = 32; tr0 = t * 64; tc0 = 0;
  } else if (bx < 248) {
    int t = bx - 216;
    src = fwm; dst = fwmBT; R = 2048; C = 64; tr0 = t * 64; tc0 = 0;
  } else {
    int blk = bx - 248;
    const float4* f4 = reinterpret_cast<const float4*>(fwm) + blk * 4096;
    float a = 0.f;
    for (int i = tid; i < 4096; i += 256) {
      float4 v = f4[i];
      a += v.x*v.x + v.y*v.y + v.z*v.z + v.w*v.w;
    }
    a = wreduce64(a);
    if ((tid & 63) == 0) red[tid >> 6] = a;
    __syncthreads();
    if (tid == 0) fn2[blk] = red[0] + red[1] + red[2] + red[3];
    return;
  }
  int TC = (C < 64) ? C : 64;
  int n = 64 * TC;
  for (int i = tid; i < n; i += 256) {
    int r = i / TC, c = i % TC;
    tl[r * 65 + c] = src[(size_t)(tr0 + r) * C + tc0 + c];
  }
  __syncthreads();
  for (int i = tid; i < n; i += 256) {
    int c = i >> 6, r = i & 63;
    dst[(size_t)(tc0 + c) * R + tr0 + r] = f2bf(tl[r * 65 + c]);
  }
}

// ---------------- MFMA fused 2-layer MLP (round-14 best: 256 thr, 2-row-tile wave) ----------------
__global__ __launch_bounds__(256, 4) void mlpm_k(
    const ushortT* __restrict__ sentB, const ushortT* __restrict__ qembB,
    const ushortT* __restrict__ W1A,
    const float* __restrict__ ueb1, const float* __restrict__ urb1,
    const float* __restrict__ ieb1, const float* __restrict__ irb1,
    const ushortT* __restrict__ W2TE, const ushortT* __restrict__ W2TR,
    const float* __restrict__ ueb2, const float* __restrict__ urb2,
    const float* __restrict__ ieb2, const float* __restrict__ irb2,
    float* __restrict__ E1, float* __restrict__ R1,
    float* __restrict__ QE1, float* __restrict__ QR1) {
  __shared__ __align__(16) ushortT Hl[32 * 520];
  int y = blockIdx.y;
  bool isQ = y >= 5;
  if (isQ && blockIdx.x >= 8) return;
  int r0 = blockIdx.x * 32, tid = threadIdx.x;
  int wave = tid >> 6, lane = tid & 63;
  int lrow = lane & 15;
  int kgrp = lane >> 4;
  const ushortT* Xb = isQ ? qembB : sentB;
  const ushortT* W1h = W1A + (size_t)y * 65536;
  const float* b1 = (y < 2) ? ueb1 + y * 512 : (y < 5) ? urb1 + (y - 2) * 512
                  : (y == 5) ? ieb1 : irb1 + (y - 6) * 512;
  bool isE = (y < 2) || (y == 5);

  int cw = wave * 128;

  short8v afr[2][4];
  #pragma unroll
  for (int rt = 0; rt < 2; ++rt) {
    const ushortT* arow = Xb + (size_t)(r0 + rt * 16 + lrow) * 128 + kgrp * 8;
    #pragma unroll
    for (int kt = 0; kt < 4; ++kt)
      afr[rt][kt] = *reinterpret_cast<const short8v*>(arow + kt * 32);
  }

  // GEMM1: 8 col-tiles; each B-frag feeds 2 MFMAs (row-tiles); 4 indep acc chains
  #pragma unroll
  for (int ct = 0; ct < 8; ++ct) {
    int c0 = cw + ct * 16;
    const ushortT* bcol = W1h + (size_t)(c0 + lrow) * 128 + kgrp * 8;
    short8v bf0 = *reinterpret_cast<const short8v*>(bcol);
    short8v bf1 = *reinterpret_cast<const short8v*>(bcol + 32);
    short8v bf2 = *reinterpret_cast<const short8v*>(bcol + 64);
    short8v bf3 = *reinterpret_cast<const short8v*>(bcol + 96);
    f32x4 aA[2] = {{0.f,0.f,0.f,0.f},{0.f,0.f,0.f,0.f}};
    f32x4 aB[2] = {{0.f,0.f,0.f,0.f},{0.f,0.f,0.f,0.f}};
    #pragma unroll
    for (int rt = 0; rt < 2; ++rt) {
      aA[rt] = __builtin_amdgcn_mfma_f32_16x16x32_bf16(afr[rt][0], bf0, aA[rt], 0, 0, 0);
      aB[rt] = __builtin_amdgcn_mfma_f32_16x16x32_bf16(afr[rt][1], bf1, aB[rt], 0, 0, 0);
      aA[rt] = __builtin_amdgcn_mfma_f32_16x16x32_bf16(afr[rt][2], bf2, aA[rt], 0, 0, 0);
      aB[rt] = __builtin_amdgcn_mfma_f32_16x16x32_bf16(afr[rt][3], bf3, aB[rt], 0, 0, 0);
    }
    int lcol = c0 + lrow;
    float bb = b1[lcol];
    #pragma unroll
    for (int rt = 0; rt < 2; ++rt)
      #pragma unroll
      for (int i = 0; i < 4; ++i) {
        float hv = ftanh(aA[rt][i] + aB[rt][i] + bb);
        Hl[(rt * 16 + kgrp * 4 + i) * 520 + lcol] = f2bf(hv);
      }
  }
  __syncthreads();

  if (isE) {
    int slot = (y == 5) ? 2 : y;
    const ushortT* W2h = W2TE + (size_t)slot * 32768;
    const float* b2 = (y == 5) ? ieb2 : ueb2 + y * 64;
    float* Out = (y == 5) ? QE1 : E1 + (size_t)y * 491520;
    int rt = wave >> 1, cb = (wave & 1) * 32;
    f32x4 accA[2] = {{0.f,0.f,0.f,0.f},{0.f,0.f,0.f,0.f}};
    f32x4 accB[2] = {{0.f,0.f,0.f,0.f},{0.f,0.f,0.f,0.f}};
    #pragma unroll
    for (int kt = 0; kt < 16; kt += 2) {
      int kb0 = kt * 32 + kgrp * 8;
      int kb1 = kb0 + 32;
      short8v a0 = *reinterpret_cast<const short8v*>(&Hl[(rt * 16 + lrow) * 520 + kb0]);
      short8v a1 = *reinterpret_cast<const short8v*>(&Hl[(rt * 16 + lrow) * 520 + kb1]);
      #pragma unroll
      for (int t = 0; t < 2; ++t) {
        const ushortT* wc = W2h + (size_t)(cb + t * 16 + lrow) * 512;
        short8v b0 = *reinterpret_cast<const short8v*>(wc + kb0);
        short8v b1v = *reinterpret_cast<const short8v*>(wc + kb1);
        accA[t] = __builtin_amdgcn_mfma_f32_16x16x32_bf16(a0, b0, accA[t], 0, 0, 0);
        accB[t] = __builtin_amdgcn_mfma_f32_16x16x32_bf16(a1, b1v, accB[t], 0, 0, 0);
      }
    }
    #pragma unroll
    for (int t = 0; t < 2; ++t) {
      int col = cb + t * 16 + lrow;
      float bb = b2[col];
      #pragma unroll
      for (int i = 0; i < 4; ++i) {
        int grow = r0 + rt * 16 + kgrp * 4 + i;
        Out[(size_t)grow * 64 + col] = ftanh(accA[t][i] + accB[t][i] + bb);
      }
    }
  } else {
    int slot = (y < 5) ? (y - 2) : (3 + y - 6);
    const ushortT* W2h = W2TR + (size_t)slot * 16384;
    const float* b2 = (y < 5) ? urb2 + (y - 2) * 32 : irb2 + (y - 6) * 32;
    float* Out = (y < 5) ? R1 + (size_t)(y - 2) * 245760 : QR1 + (size_t)(y - 6) * 8192;
    int rt = wave >> 1, cb = (wave & 1) * 16;
    f32x4 accA = {0.f, 0.f, 0.f, 0.f}, accB = {0.f, 0.f, 0.f, 0.f};
    const ushortT* wc = W2h + (size_t)(cb + lrow) * 512;
    #pragma unroll
    for (int kt = 0; kt < 16; kt += 2) {
      int kb0 = kt * 32 + kgrp * 8;
      int kb1 = kb0 + 32;
      short8v a0 = *reinterpret_cast<const short8v*>(&Hl[(rt * 16 + lrow) * 520 + kb0]);
      short8v a1 = *reinterpret_cast<const short8v*>(&Hl[(rt * 16 + lrow) * 520 + kb1]);
      short8v b0 = *reinterpret_cast<const short8v*>(wc + kb0);
      short8v b1v = *reinterpret_cast<const short8v*>(wc + kb1);
      accA = __builtin_amdgcn_mfma_f32_16x16x32_bf16(a0, b0, accA, 0, 0, 0);
      accB = __builtin_amdgcn_mfma_f32_16x16x32_bf16(a1, b1v, accB, 0, 0, 0);
    }
    int col = cb + lrow;
    float bb = b2[col];
    #pragma unroll
    for (int i = 0; i < 4; ++i) {
      int grow = r0 + rt * 16 + kgrp * 4 + i;
      Out[(size_t)grow * 32 + col] = ftanh(accA[i] + accB[i] + bb);
    }
  }
}

// ---------------- MFMA P-stage (bx<480) + G-stage (bx>=480) ----------------
__global__ __launch_bounds__(256) void pstage_k(const ushortT* __restrict__ fwmBT,
    const float* __restrict__ e1g, const float* __restrict__ e2g,
    const float* __restrict__ r1g, const float* __restrict__ r2g, const float* __restrict__ r3g,
    const float* __restrict__ qr1g, const float* __restrict__ qr2g, const float* __restrict__ qr3g,
    float* __restrict__ Pp, float* __restrict__ Gg) {
  __shared__ __align__(16) float e1t[16 * 68], e2t[16 * 68];
  int bx = blockIdx.x, tid = threadIdx.x;
  int wave = tid >> 6, lane = tid & 63;
  int c = lane & 15, kg = lane >> 4;
  int f0 = wave * 16;
  const f32x4 zero = {0,0,0,0};

  if (bx >= 480) {
    int b = bx - 480;
    short8v qa = {0,0,0,0,0,0,0,0};
    if (c < 3) {
      const float* qr = ((c == 0) ? qr1g : (c == 1) ? qr2g : qr3g) + (size_t)b * 32 + kg * 8;
      ushortT* p = (ushortT*)&qa;
      #pragma unroll
      for (int j = 0; j < 8; ++j) p[j] = f2bf(qr[j]);
    }
    const ushortT* bbase = fwmBT + (size_t)(f0 + c) * 2048 + kg * 8;
    float* g0 = Gg + (size_t)b * 4096 + f0 + c;
    for (int e = 0; e < 64; ++e) {
      short8v B = *reinterpret_cast<const short8v*>(bbase + (size_t)e * 32);
      f32x4 T = __builtin_amdgcn_mfma_f32_16x16x32_bf16(qa, B, zero, 0, 0, 0);
      if (kg == 0) {
        g0[e * 64]           = T[0];
        g0[1048576 + e * 64] = T[1];
        g0[2097152 + e * 64] = T[2];
      }
    }
    return;
  }

  int rb = bx;
  {
    int row = tid >> 4, c4 = tid & 15;
    float4 v1 = *reinterpret_cast<const float4*>(e1g + ((size_t)rb * 16 + row) * 64 + c4 * 4);
    float4 v2 = *reinterpret_cast<const float4*>(e2g + ((size_t)rb * 16 + row) * 64 + c4 * 4);
    *reinterpret_cast<float4*>(&e1t[row * 68 + c4 * 4]) = v1;
    *reinterpret_cast<float4*>(&e2t[row * 68 + c4 * 4]) = v2;
  }
  size_t rbase = ((size_t)rb * 16 + c) * 32 + kg * 8;
  short8v rA, rB, rC;
  {
    float4 x0 = *reinterpret_cast<const float4*>(r1g + rbase);
    float4 x1 = *reinterpret_cast<const float4*>(r1g + rbase + 4);
    ushortT* p = (ushortT*)&rA;
    p[0]=f2bf(x0.x); p[1]=f2bf(x0.y); p[2]=f2bf(x0.z); p[3]=f2bf(x0.w);
    p[4]=f2bf(x1.x); p[5]=f2bf(x1.y); p[6]=f2bf(x1.z); p[7]=f2bf(x1.w);
    x0 = *reinterpret_cast<const float4*>(r2g + rbase);
    x1 = *reinterpret_cast<const float4*>(r2g + rbase + 4);
    p = (ushortT*)&rB;
    p[0]=f2bf(x0.x); p[1]=f2bf(x0.y); p[2]=f2bf(x0.z); p[3]=f2bf(x0.w);
    p[4]=f2bf(x1.x); p[5]=f2bf(x1.y); p[6]=f2bf(x1.z); p[7]=f2bf(x1.w);
    x0 = *reinterpret_cast<const float4*>(r3g + rbase);
    x1 = *reinterpret_cast<const float4*>(r3g + rbase + 4);
    p = (ushortT*)&rC;
    p[0]=f2bf(x0.x); p[1]=f2bf(x0.y); p[2]=f2bf(x0.z); p[3]=f2bf(x0.w);
    p[4]=f2bf(x1.x); p[5]=f2bf(x1.y); p[6]=f2bf(x1.z); p[7]=f2bf(x1.w);
  }
  __syncthreads();
  const ushortT* bbase = fwmBT + (size_t)(f0 + c) * 2048 + kg * 8;
  f32x4 P1 = {0,0,0,0}, P2 = {0,0,0,0}, P3 = {0,0,0,0};
  int r0 = kg * 4;
  for (int e4 = 0; e4 < 16; ++e4) {
    float4 ea[4], eb[4];
    #pragma unroll
    for (int i = 0; i < 4; ++i) {
      ea[i] = *reinterpret_cast<const float4*>(&e1t[(r0 + i) * 68 + e4 * 4]);
      eb[i] = *reinterpret_cast<const float4*>(&e2t[(r0 + i) * 68 + e4 * 4]);
    }
    #pragma unroll
    for (int sub = 0; sub < 4; ++sub) {
      int e = e4 * 4 + sub;
      short8v B = *reinterpret_cast<const short8v*>(bbase + (size_t)e * 32);
      f32x4 T1 = __builtin_amdgcn_mfma_f32_16x16x32_bf16(rA, B, zero, 0, 0, 0);
      f32x4 T2 = __builtin_amdgcn_mfma_f32_16x16x32_bf16(rB, B, zero, 0, 0, 0);
      f32x4 T3 = __builtin_amdgcn_mfma_f32_16x16x32_bf16(rC, B, zero, 0, 0, 0);
      #pragma unroll
      for (int i = 0; i < 4; ++i) {
        float e1v = reinterpret_cast<const float*>(&ea[i])[sub];
        float e2v = reinterpret_cast<const float*>(&eb[i])[sub];
        P1[i] += e1v * T1[i];
        P2[i] += e1v * T2[i];
        P3[i] += e2v * T3[i];
      }
    }
  }
  #pragma unroll
  for (int i = 0; i < 4; ++i) {
    size_t row = (size_t)rb * 16 + kg * 4 + i;
    Pp[row * 64 + f0 + c]               = P1[i];
    Pp[491520 + row * 64 + f0 + c]      = P2[i];
    Pp[2 * 491520 + row * 64 + f0 + c]  = P3[i];
  }
}

// ---------------- scan: gram(bf16 hi/lo M) + MFMA propagation + inference ----------------
__global__ __launch_bounds__(1024) void scan_k(
    const float* __restrict__ Pp, const float* __restrict__ Gg,
    const float* __restrict__ e1g, const float* __restrict__ e2g,
    const float* __restrict__ r1g, const float* __restrict__ r2g, const float* __restrict__ r3g,
    const float* __restrict__ qe1g, const float* __restrict__ qr1g, const float* __restrict__ qr2g,
    const float* __restrict__ qr3g, const float* __restrict__ fn2p,
    const float* __restrict__ lng, const float* __restrict__ lnb, const float* __restrict__ Zg,
    float* __restrict__ out) {
  __shared__ __align__(16) ushortT MBs[2][9][1280];     // [hi/lo][ph*3+kk][row*40+col] bf16 M
  __shared__ __align__(16) ushortT vTb[2][2][2560];     // [buf][hi/lo][f*40+sp]
  __shared__ float wLx[2048];                            // w relay
  __shared__ float partBuf[1024];
  __shared__ __align__(16) float e1L[2040], e2L[2040];  // [30][68]
  __shared__ __align__(16) float v1L[2040], v2L[2040], v3L[2040];
  __shared__ __align__(16) float r1L[1080], r2L[1080], r3L[1080];  // [30][36]
  __shared__ float uv[64], qv[96], alf[96], siL[64], rqL[272];
  __shared__ float redL[16];
  int b = blockIdx.x, tid = threadIdx.x;
  int wave = tid >> 6, lane = tid & 63;
  int col = lane & 15, kgrp = lane >> 4;
  bool wact = wave < 12;
  int kk = wave >> 2, idx = wave & 3, st = idx >> 1, fp = idx & 1;

  // ---- staging ----
  for (int i = tid; i < 1680; i += 1024) {
    if (i < 480) {
      int ss = i >> 4, c4 = i & 15;
      *reinterpret_cast<float4*>(&e1L[ss * 68 + c4 * 4]) =
          *reinterpret_cast<const float4*>(e1g + (size_t)b * 1920 + i * 4);
    } else if (i < 960) {
      int j = i - 480;
      int ss = j >> 4, c4 = j & 15;
      *reinterpret_cast<float4*>(&e2L[ss * 68 + c4 * 4]) =
          *reinterpret_cast<const float4*>(e2g + (size_t)b * 1920 + j * 4);
    } else {
      int j = i - 960;
      int which = j / 240, jj = j - which * 240;
      int ss = jj >> 3, c4 = jj & 7;
      float* dstL = (which == 0) ? r1L : (which == 1) ? r2L : r3L;
      const float* srcG = (which == 0) ? r1g : (which == 1) ? r2g : r3g;
      *reinterpret_cast<float4*>(&dstL[ss * 36 + c4 * 4]) =
          *reinterpret_cast<const float4*>(srcG + (size_t)b * 960 + jj * 4);
    }
  }
  if (tid >= 128 && tid < 224) {
    int t = tid - 128, sst = t >> 5, k = t & 31;
    const float* qrg = (sst == 0) ? qr1g : ((sst == 1) ? qr2g : qr3g);
    qv[t] = qrg[(size_t)b * 32 + k];
  }
  for (int i = tid; i < 7200; i += 1024) {
    int m = i / 400, rr = i - m * 400;
    int hl = m / 9, mat = m - hl * 9;
    int r, c;
    if (rr < 320) { r = rr / 10; c = 30 + rr % 10; }
    else { int q = rr - 320; r = 30 + q / 40; c = q % 40; }
    MBs[hl][mat][r * 40 + c] = 0;
  }
  f32x4 Ht[2] = {{0.f,0.f,0.f,0.f},{0.f,0.f,0.f,0.f}};
  float aT[2][4] = {{0,0,0,0},{0,0,0,0}};
  if (wact) {
    #pragma unroll
    for (int t = 0; t < 2; ++t)
      #pragma unroll
      for (int i = 0; i < 4; ++i) {
        int srow = st * 16 + kgrp * 4 + i;
        int f = (fp * 2 + t) * 16 + col;
        Ht[t][i] = (srow < 30) ? Pp[(size_t)kk * 491520 + (size_t)b * 1920 + srow * 64 + f] : 0.f;
      }
  }
  __syncthreads();

  // ---- gram -> bf16 hi/lo M ; rqL ----
  if (tid < 900) {
    int si = tid / 30, sj = tid - si * 30;
    float g11 = 0, g12 = 0, g21 = 0, g22 = 0;
    {
      const float4* A1 = reinterpret_cast<const float4*>(&e1L[si * 68]);
      const float4* A2 = reinterpret_cast<const float4*>(&e2L[si * 68]);
      const float4* C1 = reinterpret_cast<const float4*>(&e1L[sj * 68]);
      const float4* C2 = reinterpret_cast<const float4*>(&e2L[sj * 68]);
      #pragma unroll 4
      for (int i = 0; i < 16; ++i) {
        float4 a1v = A1[i], a2v = A2[i], c1v = C1[i], c2v = C2[i];
        g11 += dot4(a1v, c1v); g12 += dot4(a1v, c2v);
        g21 += dot4(a2v, c1v); g22 += dot4(a2v, c2v);
      }
    }
    float R11=0,R12=0,R13=0,R21=0,R22=0,R23=0,R31=0,R32=0,R33=0;
    {
      const float4* X1 = reinterpret_cast<const float4*>(&r1L[si * 36]);
      const float4* X2 = reinterpret_cast<const float4*>(&r2L[si * 36]);
      const float4* X3 = reinterpret_cast<const float4*>(&r3L[si * 36]);
      const float4* Y1 = reinterpret_cast<const float4*>(&r1L[sj * 36]);
      const float4* Y2 = reinterpret_cast<const float4*>(&r2L[sj * 36]);
      const float4* Y3 = reinterpret_cast<const float4*>(&r3L[sj * 36]);
      #pragma unroll 4
      for (int i = 0; i < 8; ++i) {
        float4 x1 = X1[i], x2 = X2[i], x3 = X3[i];
        float4 y1 = Y1[i], y2 = Y2[i], y3 = Y3[i];
        R11 += dot4(x1, y1); R12 += dot4(x1, y2); R13 += dot4(x1, y3);
        R21 += dot4(x2, y1); R22 += dot4(x2, y2); R23 += dot4(x2, y3);
        R31 += dot4(x3, y1); R32 += dot4(x3, y2); R33 += dot4(x3, y3);
      }
    }
    float vals[9];
    vals[0] = g11 * R11; vals[1] = g11 * R21; vals[2] = g21 * R31;
    vals[3] = g11 * R12; vals[4] = g11 * R22; vals[5] = g21 * R32;
    vals[6] = g12 * R13; vals[7] = g12 * R23; vals[8] = g22 * R33;
    int o = si * 40 + sj;
    #pragma unroll
    for (int m = 0; m < 9; ++m) {
      ushortT hi = f2bf(vals[m]);
      float res = vals[m] - bf2f(hi);
      MBs[0][m][o] = hi;
      MBs[1][m][o] = f2bf(res);
    }
  } else {
    #pragma unroll
    for (int ch = 0; ch < 3; ++ch) {
      int t = (tid - 900) + ch * 124;
      if (t < 270) {
        int sst = t / 90, rem = t - sst * 90;
        int k = rem / 30, s2 = rem - k * 30;
        const float* rL = (k == 0) ? r1L : (k == 1) ? r2L : r3L;
        const float* qp = qv + sst * 32;
        float a = 0.f;
        #pragma unroll 8
        for (int r = 0; r < 32; ++r) a += rL[s2 * 36 + r] * qp[r];
        rqL[sst * 90 + k * 30 + s2] = a;
      }
    }
  }
  float eP[2][4] = {{0,0,0,0},{0,0,0,0}};
  if (wact && kk != 1) {
    const float* eSrc = (kk == 0) ? e2L : e1L;
    #pragma unroll
    for (int t = 0; t < 2; ++t)
      #pragma unroll
      for (int i = 0; i < 4; ++i) {
        int srow = st * 16 + kgrp * 4 + i;
        if (srow < 30) eP[t][i] = eSrc[srow * 68 + (fp * 2 + t) * 16 + col];
      }
  }
  __syncthreads();

  short8v Ah0, Al0, Ah1, Al1, Ah2, Al2;
  if (wact) {
    int ao = (st * 16 + col) * 40 + kgrp * 8;
    Ah0 = *reinterpret_cast<const short8v*>(&MBs[0][kk][ao]);
    Al0 = *reinterpret_cast<const short8v*>(&MBs[1][kk][ao]);
    Ah1 = *reinterpret_cast<const short8v*>(&MBs[0][3 + kk][ao]);
    Al1 = *reinterpret_cast<const short8v*>(&MBs[1][3 + kk][ao]);
    Ah2 = *reinterpret_cast<const short8v*>(&MBs[0][6 + kk][ao]);
    Al2 = *reinterpret_cast<const short8v*>(&MBs[1][6 + kk][ao]);
  }

  float n2 = 0.f;
  #pragma unroll
  for (int i = 0; i < 8; ++i) n2 += fn2p[i];
  float c0v = 1.f;

  float sav[2][4], vr[2][4];
  auto vWrite = [&](int bsel) {
    #pragma unroll
    for (int t = 0; t < 2; ++t) {
      ushortT h0 = f2bf(vr[t][0]), h1 = f2bf(vr[t][1]), h2 = f2bf(vr[t][2]), h3 = f2bf(vr[t][3]);
      float r0 = vr[t][0] - bf2f(h0), r1 = vr[t][1] - bf2f(h1);
      float r2 = vr[t][2] - bf2f(h2), r3 = vr[t][3] - bf2f(h3);
      uint2 hw, lw;
      hw.x = (unsigned)h0 | ((unsigned)h1 << 16);
      hw.y = (unsigned)h2 | ((unsigned)h3 << 16);
      lw.x = (unsigned)f2bf(r0) | ((unsigned)f2bf(r1) << 16);
      lw.y = (unsigned)f2bf(r2) | ((unsigned)f2bf(r3) << 16);
      int off = ((fp * 2 + t) * 16 + col) * 40 + st * 16 + kgrp * 4;
      *reinterpret_cast<uint2*>(&vTb[bsel][0][off]) = hw;
      *reinterpret_cast<uint2*>(&vTb[bsel][1][off]) = lw;
    }
  };
  auto mfmaPh = [&](int bsel, short8v AH, short8v AL) {
    if (wact) {
      #pragma unroll
      for (int t = 0; t < 2; ++t) {
        int off = ((fp * 2 + t) * 16 + col) * 40 + kgrp * 8;
        short8v Bh = *reinterpret_cast<const short8v*>(&vTb[bsel][0][off]);
        short8v Bl = *reinterpret_cast<const short8v*>(&vTb[bsel][1][off]);
        Ht[t] = __builtin_amdgcn_mfma_f32_16x16x32_bf16(AH, Bh, Ht[t], 0, 0, 0);
        Ht[t] = __builtin_amdgcn_mfma_f32_16x16x32_bf16(AH, Bl, Ht[t], 0, 0, 0);
        Ht[t] = __builtin_amdgcn_mfma_f32_16x16x32_bf16(AL, Bh, Ht[t], 0, 0, 0);
      }
    }
  };

  int buf = 0;
  for (int layer = 0; layer < 3; ++layer) {
    if (wact) {
      #pragma unroll
      for (int t = 0; t < 2; ++t)
        #pragma unroll
        for (int i = 0; i < 4; ++i) { sav[t][i] = Ht[t][i]; vr[t][i] = 0.f; }
      if (kk == 0) {
        int base = idx * 512 + lane * 8;
        #pragma unroll
        for (int t = 0; t < 2; ++t)
          #pragma unroll
          for (int i = 0; i < 4; ++i) wLx[base + t * 4 + i] = Ht[t][i];
      }
    }
    if (wact && kk == 0) {
      #pragma unroll
      for (int t = 0; t < 2; ++t)
        #pragma unroll
        for (int i = 0; i < 4; ++i) {
          int srow = st * 16 + kgrp * 4 + i;
          vr[t][i] = (srow < 30) ? (eP[t][i] - Ht[t][i]) : 0.f;
        }
      vWrite(buf);
    }
    __syncthreads();
    mfmaPh(buf, Ah0, Al0);
    buf ^= 1;
    if (wact && kk == 0) {
      #pragma unroll
      for (int t = 0; t < 2; ++t)
        #pragma unroll
        for (int i = 0; i < 4; ++i) aT[t][i] += vr[t][i];
    }
    if (wact && kk == 1) {
      int base = idx * 512 + lane * 8;
      #pragma unroll
      for (int t = 0; t < 2; ++t)
        #pragma unroll
        for (int i = 0; i < 4; ++i) {
          int srow = st * 16 + kgrp * 4 + i;
          vr[t][i] = (srow < 30) ? (wLx[base + t * 4 + i] - Ht[t][i]) : 0.f;
        }
      vWrite(buf);
    }
    __syncthreads();
    mfmaPh(buf, Ah1, Al1);
    buf ^= 1;
    if (wact && kk == 1) {
      #pragma unroll
      for (int t = 0; t < 2; ++t)
        #pragma unroll
        for (int i = 0; i < 4; ++i) aT[t][i] += vr[t][i];
    }
    if (wact && kk == 2) {
      #pragma unroll
      for (int t = 0; t < 2; ++t)
        #pragma unroll
        for (int i = 0; i < 4; ++i) {
          int srow = st * 16 + kgrp * 4 + i;
          vr[t][i] = (srow < 30) ? (eP[t][i] - Ht[t][i]) : 0.f;
        }
      vWrite(buf);
    }
    __syncthreads();
    mfmaPh(buf, Ah2, Al2);
    buf ^= 1;
    if (wact && kk == 2) {
      #pragma unroll
      for (int t = 0; t < 2; ++t)
        #pragma unroll
        for (int i = 0; i < 4; ++i) aT[t][i] += vr[t][i];
    }
    float local = 0.f;
    if (wact) {
      #pragma unroll
      for (int t = 0; t < 2; ++t)
        #pragma unroll
        for (int i = 0; i < 4; ++i) {
          int srow = st * 16 + kgrp * 4 + i;
          if (srow < 30) local += vr[t][i] * (sav[t][i] + Ht[t][i]);
        }
    }
    local = wreduce64(local);
    if ((tid & 63) == 0) redL[tid >> 6] = local;
    __syncthreads();
    float tot = n2;
    #pragma unroll
    for (int i = 0; i < 16; ++i) tot += redL[i];
    float fn = fmaxf(sqrtf(tot), 1.f);
    float inv = 1.f / fn;
    n2 = tot * inv * inv;
    c0v *= inv;
    if (wact) {
      #pragma unroll
      for (int t = 0; t < 2; ++t)
        #pragma unroll
        for (int i = 0; i < 4; ++i) { Ht[t][i] *= inv; aT[t][i] *= inv; }
    }
  }

  if (wact) {
    float* dstA = (kk == 0) ? v1L : (kk == 1) ? v2L : v3L;
    #pragma unroll
    for (int t = 0; t < 2; ++t)
      #pragma unroll
      for (int i = 0; i < 4; ++i) {
        int srow = st * 16 + kgrp * 4 + i;
        if (srow < 30) dstA[srow * 68 + (fp * 2 + t) * 16 + col] = aT[t][i];
      }
  }
  if (tid < 64) { uv[tid] = qe1g[(size_t)b * 64 + tid]; siL[tid] = 0.f; }
  __syncthreads();

  int s = tid >> 5;
  bool act = s < 30;
  float* partL = partBuf;
  int k32 = tid & 31;
  for (int stg = 0; stg < 3; ++stg) {
    if (act) {
      float u0 = uv[k32], u1 = uv[k32 + 32];
      float eu1 = e1L[s * 68 + k32] * u0 + e1L[s * 68 + k32 + 32] * u1;
      float eu2 = e2L[s * 68 + k32] * u0 + e2L[s * 68 + k32 + 32] * u1;
      #pragma unroll
      for (int d = 16; d > 0; d >>= 1) {
        eu1 += __shfl_down(eu1, d, 32); eu2 += __shfl_down(eu2, d, 32);
      }
      if (k32 == 0) {
        alf[s]      = eu1 * rqL[stg * 90 + s];
        alf[32 + s] = eu1 * rqL[stg * 90 + 30 + s];
        alf[64 + s] = eu2 * rqL[stg * 90 + 60 + s];
      }
    }
    __syncthreads();
    {
      int p = tid >> 6, f = tid & 63;
      float part = 0.f;
      if (p < 12) {
        int start = (p < 6) ? p * 3 : 18 + (p - 6) * 2;
        int cnt = (p < 6) ? 3 : 2;
        for (int q = 0; q < cnt; ++q) {
          int sp = start + q;
          part += alf[sp] * v1L[sp * 68 + f] + alf[32 + sp] * v2L[sp * 68 + f]
                + alf[64 + sp] * v3L[sp * 68 + f];
        }
      } else {
        int e0 = (p - 12) * 16;
        const float* Gp = Gg + (size_t)stg * 1048576 + (size_t)b * 4096 + (size_t)e0 * 64 + f;
        float F = 0.f;
        #pragma unroll 4
        for (int e = 0; e < 16; ++e) F += uv[e0 + e] * Gp[e * 64];
        part = c0v * F;
      }
      partL[p * 64 + f] = part;
    }
    __syncthreads();
    if (tid < 64) {
      float raw = 0.f;
      #pragma unroll
      for (int p = 0; p < 16; ++p) raw += partL[p * 64 + tid];
      float mean = wreduce64(raw) * (1.f / 64.f);
      float d = raw - mean;
      float var = wreduce64(d * d) * (1.f / 63.f);
      float y = lng[stg * 64 + tid] * d / (sqrtf(var) + 1e-6f) + lnb[stg * 64 + tid];
      siL[tid] += y;
      uv[tid] = y;
    }
    __syncthreads();
  }
  if (tid < 9) {
    float o = 0.f;
    for (int ff = 0; ff < 64; ++ff) o += siL[ff] * Zg[ff * 9 + tid];
    out[(size_t)b * 9 + tid] = o;
  }
}

extern "C" void kernel_launch(void* const* d_in, const int* in_sizes, int n_in,
                              void* d_out, int out_size, void* d_ws, size_t ws_size,
                              hipStream_t stream) {
  const int*   story = (const int*)d_in[0];
  const int*   query = (const int*)d_in[1];
  const float* WE    = (const float*)d_in[2];
  const float* PE    = (const float*)d_in[3];
  const float* ueW1  = (const float*)d_in[4];
  const float* ueb1  = (const float*)d_in[5];
  const float* ueW2  = (const float*)d_in[6];
  const float* ueb2  = (const float*)d_in[7];
  const float* urW1  = (const float*)d_in[8];
  const float* urb1  = (const float*)d_in[9];
  const float* urW2  = (const float*)d_in[10];
  const float* urb2  = (const float*)d_in[11];
  const float* fwm   = (const float*)d_in[12];
  const float* ieW1  = (const float*)d_in[13];
  const float* ieb1  = (const float*)d_in[14];
  const float* ieW2  = (const float*)d_in[15];
  const float* ieb2  = (const float*)d_in[16];
  const float* irW1  = (const float*)d_in[17];
  const float* irb1  = (const float*)d_in[18];
  const float* irW2  = (const float*)d_in[19];
  const float* irb2  = (const float*)d_in[20];
  const float* lng   = (const float*)d_in[21];
  const float* lnb   = (const float*)d_in[22];
  const float* Z     = (const float*)d_in[23];
  float* W = (float*)d_ws;
  float* out = (float*)d_out;

  ushortT* sentB = (ushortT*)(W + OF_SENTB);
  ushortT* qembB = (ushortT*)(W + OF_QEMBB);
  ushortT* W1A   = (ushortT*)(W + OF_W1A);
  ushortT* W2TE  = (ushortT*)(W + OF_W2TE);
  ushortT* W2TR  = (ushortT*)(W + OF_W2TR);
  ushortT* fwmBT = (ushortT*)(W + OF_FWMB);

  prep_k<<<4232, 256, 0, stream>>>(story, query, WE, PE,
      ueW1, urW1, ieW1, irW1, ueW2, urW2, ieW2, irW2, fwm,
      sentB, qembB, W1A, W2TE, W2TR, fwmBT, W + OF_FN2);

  mlpm_k<<<dim3(240, 9), 256, 0, stream>>>(sentB, qembB, W1A,
      ueb1, urb1, ieb1, irb1, W2TE, W2TR, ueb2, urb2, ieb2, irb2,
      W + OF_E1, W + OF_R1, W + OF_QE1, W + OF_QR1);

  pstage_k<<<736, 256, 0, stream>>>(fwmBT, W + OF_E1, W + OF_E1 + 491520,
      W + OF_R1, W + OF_R1 + 245760, W + OF_R1 + 2 * 245760,
      W + OF_QR1, W + OF_QR1 + 8192, W + OF_QR1 + 16384,
      W + OF_PP, W + OF_G);

  scan_k<<<NB, 1024, 0, stream>>>(W + OF_PP, W + OF_G,
      W + OF_E1, W + OF_E1 + 491520,
      W + OF_R1, W + OF_R1 + 245760, W + OF_R1 + 2 * 245760,
      W + OF_QE1, W + OF_QR1, W + OF_QR1 + 8192, W + OF_QR1 + 16384,
      W + OF_FN2, lng, lnb, Z, out);
}